// Round 5
// baseline (376.909 us; speedup 1.0000x reference)
//
#include <hip/hip_runtime.h>
#include <math.h>

#define B_ 4
#define S_ 2048
#define D_ 1024
#define E_ 16
#define DH_ 64
#define TOPK_ 8
#define MAXLEN_ 1228
#define MPAD_ 1280
#define CAPF 4.0f
#define EPS_ 1e-6f

typedef __attribute__((ext_vector_type(8))) short bf16x8;
typedef __attribute__((ext_vector_type(4))) float f32x4;

__device__ inline f32x4 mfma16(bf16x8 a, bf16x8 b, f32x4 c) {
  return __builtin_amdgcn_mfma_f32_16x16x32_bf16(a, b, c, 0, 0, 0);
}
__device__ inline float bf2f(unsigned short u) {
  return __uint_as_float(((unsigned)u) << 16);
}
__device__ inline unsigned short f2bf(float f) {
  unsigned u = __float_as_uint(f);
  unsigned r = (u + 0x7FFFu + ((u >> 16) & 1u)) >> 16;
  return (unsigned short)r;
}
__device__ inline ushort4 pk4(float4 v) {
  ushort4 r;
  r.x = f2bf(v.x); r.y = f2bf(v.y); r.z = f2bf(v.z); r.w = f2bf(v.w);
  return r;
}
// XOR-swizzled LDS addressing (byte offsets), 128B rows.
__device__ inline int swz128(int row, int off) { return row * 128 + (off ^ ((row & 7) << 4)); }

// ---------------- one-time converts ----------------
__global__ __launch_bounds__(256) void cvt_x_kernel(
    const float* __restrict__ X, unsigned short* __restrict__ Xb) {
  size_t i = ((size_t)blockIdx.x * 256 + threadIdx.x) * 8;
  float4 a = *reinterpret_cast<const float4*>(X + i);
  float4 b = *reinterpret_cast<const float4*>(X + i + 4);
  *reinterpret_cast<ushort4*>(Xb + i) = pk4(a);
  *reinterpret_cast<ushort4*>(Xb + i + 4) = pk4(b);
}

// W_qkv[e][1024 k][192 n] f32 -> Wt[e][192 n][1024 k] bf16
__global__ __launch_bounds__(256) void cvt_wqkv_kernel(
    const float* __restrict__ W, unsigned short* __restrict__ Wt) {
  __shared__ short T[192][40];
  int e = blockIdx.y, k0 = blockIdx.x * 32;
  const float* Wp = W + (size_t)e * D_ * 192 + (size_t)k0 * 192;
  int tid = threadIdx.x;
#pragma unroll
  for (int it = 0; it < 24; it++) {
    int idx = tid + it * 256;  // 0..6143
    int kr = idx / 192, n = idx % 192;
    T[n][kr] = (short)f2bf(Wp[(size_t)kr * 192 + n]);
  }
  __syncthreads();
  unsigned short* Wo = Wt + (size_t)e * 192 * 1024 + k0;
#pragma unroll
  for (int it = 0; it < 3; it++) {
    int idx = tid + it * 256;  // 0..767
    int n = idx >> 2, c = idx & 3;
    bf16x8 v = *reinterpret_cast<bf16x8*>(&T[n][c * 8]);
    *reinterpret_cast<bf16x8*>(Wo + (size_t)n * 1024 + c * 8) = v;
  }
}

// W_ff[e][64 k][1024 n] f32 -> Wt[e][1024 n][64 k] bf16
__global__ __launch_bounds__(256) void cvt_wff_kernel(
    const float* __restrict__ W, unsigned short* __restrict__ Wt) {
  __shared__ short T[64][72];
  int e = blockIdx.y, n0 = blockIdx.x * 64;
  const float* Wp = W + (size_t)e * DH_ * D_;
  int tid = threadIdx.x;
#pragma unroll
  for (int it = 0; it < 16; it++) {
    int idx = tid + it * 256;  // 0..4095
    int k = idx >> 6, n = idx & 63;
    T[n][k] = (short)f2bf(Wp[(size_t)k * D_ + n0 + n]);
  }
  __syncthreads();
  unsigned short* Wo = Wt + (size_t)e * D_ * DH_ + (size_t)n0 * DH_;
#pragma unroll
  for (int it = 0; it < 2; it++) {
    int idx = tid + it * 256;  // 0..511
    int n = idx >> 3, c = idx & 7;
    bf16x8 v = *reinterpret_cast<bf16x8*>(&T[n][c * 8]);
    *reinterpret_cast<bf16x8*>(Wo + (size_t)n * DH_ + c * 8) = v;
  }
}

// ---------------- Kernel 1: gating -> masked_t[e][b][s] ----------------
__global__ __launch_bounds__(256) void gate_kernel(
    const float* __restrict__ X, const float* __restrict__ wg,
    const float* __restrict__ bg, float* __restrict__ masked_t) {
  int token = blockIdx.x * 4 + (threadIdx.x >> 6);  // b*S + s
  int lane = threadIdx.x & 63;
  int b = token / S_, s = token % S_;
  const float* xrow = X + (size_t)token * D_;
  float acc[E_];
#pragma unroll
  for (int e = 0; e < E_; e++) acc[e] = 0.f;
#pragma unroll
  for (int d0 = 0; d0 < D_; d0 += 256) {
    int d = d0 + lane * 4;
    float4 xv = *reinterpret_cast<const float4*>(xrow + d);
    const float* w0 = wg + (size_t)d * E_;
#pragma unroll
    for (int e = 0; e < E_; e++)
      acc[e] += xv.x * w0[e] + xv.y * w0[E_ + e] + xv.z * w0[2 * E_ + e] +
                xv.w * w0[3 * E_ + e];
  }
#pragma unroll
  for (int e = 0; e < E_; e++) {
    float v = acc[e];
    for (int off = 32; off; off >>= 1) v += __shfl_xor(v, off);
    acc[e] = v;
  }
  if (lane == 0) {
    float lg[E_], sc[E_], mx = -1e30f;
#pragma unroll
    for (int e = 0; e < E_; e++) {
      lg[e] = acc[e] + bg[e];
      mx = fmaxf(mx, lg[e]);
    }
    float den = 0.f;
#pragma unroll
    for (int e = 0; e < E_; e++) {
      sc[e] = expf(lg[e] - mx);
      den += sc[e];
    }
#pragma unroll
    for (int e = 0; e < E_; e++) sc[e] /= den;
#pragma unroll
    for (int e = 0; e < E_; e++) {
      int rank = 0;
      for (int j = 0; j < E_; j++)
        if (lg[j] > lg[e] || (lg[j] == lg[e] && j < e)) rank++;
      float m = (rank < TOPK_) ? sc[e] : 0.f;
      masked_t[((size_t)e * B_ + b) * S_ + s] = m;
    }
  }
}

// ---------------- Kernel 2: route_t = masked/denom*CAP ----------------
__global__ __launch_bounds__(256) void route_kernel(
    const float* __restrict__ masked_t, float* __restrict__ route_t) {
  int i = blockIdx.x * blockDim.x + threadIdx.x;  // over E*S
  if (i >= E_ * S_) return;
  int e = i / S_, s = i % S_;
  float v[B_];
  float d = EPS_;
#pragma unroll
  for (int b = 0; b < B_; b++) {
    v[b] = masked_t[((size_t)e * B_ + b) * S_ + s];
    d += v[b];
  }
#pragma unroll
  for (int b = 0; b < B_; b++)
    route_t[((size_t)e * B_ + b) * S_ + s] = v[b] / d * CAPF;
}

// ---------------- Kernel 3: top-MAXLEN selection per (e,b) ----------------
__global__ __launch_bounds__(1024) void select_kernel(
    const float* __restrict__ route_t, int* __restrict__ seq_ids) {
  __shared__ unsigned long long keys[S_];
  __shared__ int flags[S_];
  __shared__ int sA[S_], sB[S_];
  int eb = blockIdx.x;
  const float* r = route_t + (size_t)eb * S_;
  int tid = threadIdx.x;
  for (int i = tid; i < S_; i += 1024) {
    unsigned int fb = __float_as_uint(r[i]);  // monotonic, r >= 0
    keys[i] = ((unsigned long long)fb << 32) | (unsigned int)(S_ - 1 - i);
  }
  __syncthreads();
  for (int k = 2; k <= S_; k <<= 1) {
    for (int j = k >> 1; j > 0; j >>= 1) {
      for (int i = tid; i < S_; i += 1024) {
        int ixj = i ^ j;
        if (ixj > i) {
          bool desc = ((i & k) == 0);
          unsigned long long a = keys[i], c = keys[ixj];
          bool sw = desc ? (a < c) : (a > c);
          if (sw) { keys[i] = c; keys[ixj] = a; }
        }
      }
      __syncthreads();
    }
  }
  for (int i = tid; i < S_; i += 1024) flags[i] = 0;
  __syncthreads();
  for (int i = tid; i < MAXLEN_; i += 1024) {
    int s = S_ - 1 - (int)(keys[i] & 0xFFFFFFFFull);
    flags[s] = 1;
  }
  __syncthreads();
  for (int i = tid; i < S_; i += 1024) sA[i] = flags[i];
  __syncthreads();
  int* src = sA;
  int* dst = sB;
  for (int off = 1; off < S_; off <<= 1) {
    for (int i = tid; i < S_; i += 1024)
      dst[i] = src[i] + ((i >= off) ? src[i - off] : 0);
    __syncthreads();
    int* t = src; src = dst; dst = t;
  }
  int* outp = seq_ids + (size_t)eb * MAXLEN_;
  for (int i = tid; i < S_; i += 1024)
    if (flags[i]) outp[src[i] - 1] = i;
}

// ---------------- Kernel 4: gathered QKV GEMM (bf16 MFMA) ----------------
// Outputs: Qr[eb][1280][64] (x0.125), Kr[eb][1280][64], VT[eb][64][1280].
// Rows m>=MAXLEN zero-filled.
__global__ __launch_bounds__(512) void qkv_kernel(
    const unsigned short* __restrict__ Xb, const unsigned short* __restrict__ Wt,
    const int* __restrict__ seq_ids, unsigned short* __restrict__ Qr,
    unsigned short* __restrict__ Kr, unsigned short* __restrict__ VT) {
  __shared__ __align__(16) char Bt_[192 * 128];  // [192 n][64 k] bf16 swz128
  __shared__ int rows[128];
  int eb = blockIdx.y;
  int e = eb >> 2, b = eb & 3;
  int m0 = blockIdx.x * 128;
  int tid = threadIdx.x;
  int w = tid >> 6, l = tid & 63, lr = l & 15, lg = l >> 4;
  const int* sid = seq_ids + (size_t)eb * MAXLEN_;
  if (tid < 128) {
    int m = m0 + tid;
    rows[tid] = (m < MAXLEN_) ? sid[m] : 0;
  }
  __syncthreads();
  const unsigned short* Wm = Wt + (size_t)e * 192 * 1024;
  const unsigned short* aptr = Xb + (size_t)b * S_ * D_ + (size_t)rows[w * 16 + lr] * D_;
  f32x4 acc[12];
#pragma unroll
  for (int nb = 0; nb < 12; nb++) acc[nb] = (f32x4){0.f, 0.f, 0.f, 0.f};
  for (int k0 = 0; k0 < D_; k0 += 64) {
#pragma unroll
    for (int it = 0; it < 3; it++) {
      int idx = tid + it * 512;  // 0..1535
      int row = idx >> 3, c = idx & 7;
      bf16x8 v = *reinterpret_cast<const bf16x8*>(Wm + (size_t)row * 1024 + k0 + c * 8);
      *reinterpret_cast<bf16x8*>(Bt_ + swz128(row, c * 16)) = v;
    }
    __syncthreads();
#pragma unroll
    for (int ks = 0; ks < 2; ks++) {
      bf16x8 af = *reinterpret_cast<const bf16x8*>(aptr + k0 + ks * 32 + lg * 8);
#pragma unroll
      for (int nb = 0; nb < 12; nb++) {
        bf16x8 bfr = *reinterpret_cast<bf16x8*>(Bt_ + swz128(nb * 16 + lr, ks * 64 + lg * 16));
        acc[nb] = mfma16(af, bfr, acc[nb]);
      }
    }
    __syncthreads();
  }
  int mb = m0 + w * 16 + lg * 4;
  unsigned short* Qe = Qr + (size_t)eb * MPAD_ * 64;
  unsigned short* Ke = Kr + (size_t)eb * MPAD_ * 64;
  unsigned short* Ve = VT + (size_t)eb * 64 * MPAD_;
#pragma unroll
  for (int nb = 0; nb < 4; nb++) {
#pragma unroll
    for (int i = 0; i < 4; i++) {
      int m = mb + i;
      float v = (m < MAXLEN_) ? acc[nb][i] * 0.125f : 0.f;
      Qe[(size_t)m * 64 + nb * 16 + lr] = f2bf(v);
    }
  }
#pragma unroll
  for (int nb = 4; nb < 8; nb++) {
#pragma unroll
    for (int i = 0; i < 4; i++) {
      int m = mb + i;
      float v = (m < MAXLEN_) ? acc[nb][i] : 0.f;
      Ke[(size_t)m * 64 + (nb - 4) * 16 + lr] = f2bf(v);
    }
  }
#pragma unroll
  for (int nb = 8; nb < 12; nb++) {
    ushort4 pv;
    pv.x = (mb + 0 < MAXLEN_) ? f2bf(acc[nb][0]) : (unsigned short)0;
    pv.y = (mb + 1 < MAXLEN_) ? f2bf(acc[nb][1]) : (unsigned short)0;
    pv.z = (mb + 2 < MAXLEN_) ? f2bf(acc[nb][2]) : (unsigned short)0;
    pv.w = (mb + 3 < MAXLEN_) ? f2bf(acc[nb][3]) : (unsigned short)0;
    *reinterpret_cast<ushort4*>(Ve + (size_t)((nb - 8) * 16 + lr) * MPAD_ + mb) = pv;
  }
}

// ------------- Kernel 5: flash attention, bf16 MFMA, per (e,b) -------------
// q-tile 128 (8 waves x 16 q cols), k-tile 64. S^T = K.Q^T; O^T = V^T.P^T.
__global__ __launch_bounds__(512) void attn_kernel(
    const unsigned short* __restrict__ Qr, const unsigned short* __restrict__ Kr,
    const unsigned short* __restrict__ VT, unsigned short* __restrict__ ctx) {
  __shared__ __align__(16) char Ks_[64 * 128];      // [64 k][64 d] swz128
  __shared__ __align__(16) char Vt_[64 * 128];      // [64 dv][64 k] swz128
  __shared__ __align__(16) char Pl_[8 * 16 * 128];  // per-wave [16 q][64 k]
  int qb = 9 - blockIdx.x;  // longest first
  int eb = blockIdx.y;
  const unsigned short* Qe = Qr + (size_t)eb * MPAD_ * 64;
  const unsigned short* Ke = Kr + (size_t)eb * MPAD_ * 64;
  const unsigned short* Ve = VT + (size_t)eb * 64 * MPAD_;
  int tid = threadIdx.x;
  int w = tid >> 6, l = tid & 63, lr = l & 15, lg = l >> 4;
  int gq = qb * 128 + w * 16 + lr;  // this lane's q column
  bf16x8 qf[2];
  qf[0] = *reinterpret_cast<const bf16x8*>(Qe + (size_t)gq * 64 + lg * 8);
  qf[1] = *reinterpret_cast<const bf16x8*>(Qe + (size_t)gq * 64 + 32 + lg * 8);
  f32x4 acc[4];
#pragma unroll
  for (int db = 0; db < 4; db++) acc[db] = (f32x4){0.f, 0.f, 0.f, 0.f};
  float mrow = -1e30f, lsum = 0.f;
  char* Pw = Pl_ + w * 2048;
  int srow = tid >> 3, sc = (tid & 7) * 8;  // staging coords
  int ndiag = 2 * qb, ktmax = 2 * qb + 1;
  for (int kt = 0; kt <= ktmax; kt++) {
    int k0 = kt * 64;
    {
      bf16x8 kv = *reinterpret_cast<const bf16x8*>(Ke + (size_t)(k0 + srow) * 64 + sc);
      *reinterpret_cast<bf16x8*>(Ks_ + swz128(srow, sc * 2)) = kv;
      bf16x8 vv = *reinterpret_cast<const bf16x8*>(Ve + (size_t)srow * MPAD_ + k0 + sc);
      *reinterpret_cast<bf16x8*>(Vt_ + swz128(srow, sc * 2)) = vv;
    }
    __syncthreads();
    f32x4 sac[4];
#pragma unroll
    for (int kb = 0; kb < 4; kb++) {
      sac[kb] = (f32x4){0.f, 0.f, 0.f, 0.f};
#pragma unroll
      for (int ds = 0; ds < 2; ds++) {
        bf16x8 kf = *reinterpret_cast<bf16x8*>(Ks_ + swz128(kb * 16 + lr, ds * 64 + lg * 16));
        sac[kb] = mfma16(kf, qf[ds], sac[kb]);
      }
    }
    float p[16];
    float tmax = -1e30f;
    if (kt >= ndiag) {  // diagonal tiles: causal + OOB mask
#pragma unroll
      for (int kb = 0; kb < 4; kb++) {
#pragma unroll
        for (int i = 0; i < 4; i++) {
          int k = k0 + kb * 16 + lg * 4 + i;
          float s = sac[kb][i];
          if (k > gq || k >= MAXLEN_) s = -1e9f;
          p[kb * 4 + i] = s;
          tmax = fmaxf(tmax, s);
        }
      }
    } else {
#pragma unroll
      for (int kb = 0; kb < 4; kb++) {
#pragma unroll
        for (int i = 0; i < 4; i++) {
          float s = sac[kb][i];
          p[kb * 4 + i] = s;
          tmax = fmaxf(tmax, s);
        }
      }
    }
    tmax = fmaxf(tmax, __shfl_xor(tmax, 16));
    tmax = fmaxf(tmax, __shfl_xor(tmax, 32));
    if (!__all(tmax <= mrow + 8.f)) {  // T13 defer-rescale
      float mnew = fmaxf(mrow, tmax);
      float corr = __expf(mrow - mnew);
      lsum *= corr;
#pragma unroll
      for (int db = 0; db < 4; db++) acc[db] = acc[db] * corr;
      mrow = mnew;
    }
    float psum = 0.f;
#pragma unroll
    for (int j = 0; j < 16; j++) {
      p[j] = __expf(p[j] - mrow);
      psum += p[j];
    }
    psum += __shfl_xor(psum, 16);
    psum += __shfl_xor(psum, 32);
    lsum += psum;
#pragma unroll
    for (int kb = 0; kb < 4; kb++) {
#pragma unroll
      for (int ip = 0; ip < 2; ip++) {
        unsigned u = (unsigned)f2bf(p[kb * 4 + ip * 2]) |
                     ((unsigned)f2bf(p[kb * 4 + ip * 2 + 1]) << 16);
        int k = kb * 16 + lg * 4 + ip * 2;
        *reinterpret_cast<unsigned*>(Pw + swz128(lr, k * 2)) = u;
      }
    }
    bf16x8 pf[2];
#pragma unroll
    for (int ks = 0; ks < 2; ks++)
      pf[ks] = *reinterpret_cast<bf16x8*>(Pw + swz128(lr, ks * 64 + lg * 16));
#pragma unroll
    for (int db = 0; db < 4; db++) {
#pragma unroll
      for (int ks = 0; ks < 2; ks++) {
        bf16x8 vf = *reinterpret_cast<bf16x8*>(Vt_ + swz128(db * 16 + lr, ks * 64 + lg * 16));
        acc[db] = mfma16(vf, pf[ks], acc[db]);
      }
    }
    __syncthreads();
  }
  if (gq < MAXLEN_) {
    float inv = 1.f / lsum;
    unsigned short* op = ctx + ((size_t)eb * MAXLEN_ + gq) * DH_;
#pragma unroll
    for (int db = 0; db < 4; db++) {
      ushort4 pv;
      pv.x = f2bf(acc[db][0] * inv);
      pv.y = f2bf(acc[db][1] * inv);
      pv.z = f2bf(acc[db][2] * inv);
      pv.w = f2bf(acc[db][3] * inv);
      *reinterpret_cast<ushort4*>(op + db * 16 + lg * 4) = pv;
    }
  }
}

// ------- Kernel 6: FF GEMM (bf16 MFMA) -> outb[e][m][:] for batch b -------
__global__ __launch_bounds__(256) void ff_kernel(
    const unsigned short* __restrict__ ctx, const unsigned short* __restrict__ Wtff,
    const float* __restrict__ bff, unsigned short* __restrict__ outb, int b) {
  __shared__ __align__(16) char As_[128 * 128];  // [128 m][64 k] bf16 swz128
  __shared__ __align__(16) char Bt_[128 * 128];  // [128 n][64 k] bf16 swz128
  int e = blockIdx.z;
  int m0 = blockIdx.y * 128, n0 = blockIdx.x * 128;
  int tid = threadIdx.x;
  int w = tid >> 6, l = tid & 63, lr = l & 15, lg = l >> 4;
  const unsigned short* A = ctx + (size_t)(e * B_ + b) * MAXLEN_ * DH_;
  const unsigned short* Wm = Wtff + (size_t)e * D_ * DH_;
#pragma unroll
  for (int it = 0; it < 8; it++) {
    int idx = tid + it * 256;  // 0..2047
    int row = idx >> 4, kq = (idx & 15) * 4;
    int gm = m0 + row;
    if (gm >= MAXLEN_) gm = MAXLEN_ - 1;
    ushort4 av = *reinterpret_cast<const ushort4*>(A + (size_t)gm * DH_ + kq);
    *reinterpret_cast<ushort4*>(As_ + swz128(row, kq * 2)) = av;
  }
#pragma unroll
  for (int it = 0; it < 4; it++) {
    int idx = tid + it * 256;  // 0..1023
    int row = idx >> 3, c = idx & 7;
    bf16x8 v = *reinterpret_cast<const bf16x8*>(Wm + (size_t)(n0 + row) * DH_ + c * 8);
    *reinterpret_cast<bf16x8*>(Bt_ + swz128(row, c * 16)) = v;
  }
  __syncthreads();
  int wm = w >> 1, wn = w & 1;
  f32x4 acc[4][4];
#pragma unroll
  for (int mb = 0; mb < 4; mb++)
#pragma unroll
    for (int nb = 0; nb < 4; nb++) acc[mb][nb] = (f32x4){0.f, 0.f, 0.f, 0.f};
#pragma unroll
  for (int ks = 0; ks < 2; ks++) {
    bf16x8 af[4], bfr[4];
#pragma unroll
    for (int mb = 0; mb < 4; mb++)
      af[mb] = *reinterpret_cast<bf16x8*>(As_ + swz128(wm * 64 + mb * 16 + lr, ks * 64 + lg * 16));
#pragma unroll
    for (int nb = 0; nb < 4; nb++)
      bfr[nb] = *reinterpret_cast<bf16x8*>(Bt_ + swz128(wn * 64 + nb * 16 + lr, ks * 64 + lg * 16));
#pragma unroll
    for (int mb = 0; mb < 4; mb++)
#pragma unroll
      for (int nb = 0; nb < 4; nb++)
        acc[mb][nb] = mfma16(af[mb], bfr[nb], acc[mb][nb]);
  }
  float bias[4];
#pragma unroll
  for (int nb = 0; nb < 4; nb++)
    bias[nb] = bff[(size_t)e * D_ + n0 + wn * 64 + nb * 16 + lr];
#pragma unroll
  for (int mb = 0; mb < 4; mb++) {
#pragma unroll
    for (int i = 0; i < 4; i++) {
      int m = m0 + wm * 64 + mb * 16 + lg * 4 + i;
      if (m < MAXLEN_) {
        unsigned short* orow = outb + ((size_t)e * MAXLEN_ + m) * D_ + n0 + wn * 64;
#pragma unroll
        for (int nb = 0; nb < 4; nb++)
          orow[nb * 16 + lr] = f2bf(acc[mb][nb][i] + bias[nb]);
      }
    }
  }
}

// ------- Kernel 7: per-token gather (binary search) + residual + LayerNorm -
__global__ __launch_bounds__(256) void gather_ln_kernel(
    const float* __restrict__ X, const unsigned short* __restrict__ outb,
    const int* __restrict__ seq_ids, const float* __restrict__ gamma,
    const float* __restrict__ beta, float* __restrict__ out, int b) {
  __shared__ int ms[E_];
  __shared__ float w1[4], w2[4];
  int s = blockIdx.x;
  int tid = threadIdx.x;
  if (tid < E_) {
    const int* sid = seq_ids + ((size_t)tid * B_ + b) * MAXLEN_;
    int lo = 0, hi = MAXLEN_;
    while (lo < hi) {
      int mid = (lo + hi) >> 1;
      if (sid[mid] < s) lo = mid + 1; else hi = mid;
    }
    ms[tid] = (lo < MAXLEN_ && sid[lo] == s) ? lo : -1;
  }
  __syncthreads();
  const float* xr = X + ((size_t)b * S_ + s) * D_;
  float4 xv = *reinterpret_cast<const float4*>(xr + tid * 4);
  float v[4] = {xv.x, xv.y, xv.z, xv.w};
#pragma unroll
  for (int e = 0; e < E_; e++) {
    int m = ms[e];
    if (m >= 0) {
      const unsigned short* orow = outb + ((size_t)e * MAXLEN_ + m) * D_;
      ushort4 u = *reinterpret_cast<const ushort4*>(orow + tid * 4);
      v[0] += bf2f(u.x); v[1] += bf2f(u.y); v[2] += bf2f(u.z); v[3] += bf2f(u.w);
    }
  }
  float s1 = v[0] + v[1] + v[2] + v[3];
  float s2 = v[0] * v[0] + v[1] * v[1] + v[2] * v[2] + v[3] * v[3];
  for (int off = 32; off; off >>= 1) {
    s1 += __shfl_xor(s1, off);
    s2 += __shfl_xor(s2, off);
  }
  int wv = tid >> 6;
  if ((tid & 63) == 0) { w1[wv] = s1; w2[wv] = s2; }
  __syncthreads();
  s1 = w1[0] + w1[1] + w1[2] + w1[3];
  s2 = w2[0] + w2[1] + w2[2] + w2[3];
  float mu = s1 * (1.f / D_);
  float var = s2 * (1.f / D_) - mu * mu;
  float inv = rsqrtf(var + 1e-5f);
  float4 g = *reinterpret_cast<const float4*>(gamma + tid * 4);
  float4 be = *reinterpret_cast<const float4*>(beta + tid * 4);
  float4 o;
  o.x = (v[0] - mu) * inv * g.x + be.x;
  o.y = (v[1] - mu) * inv * g.y + be.y;
  o.z = (v[2] - mu) * inv * g.z + be.z;
  o.w = (v[3] - mu) * inv * g.w + be.w;
  *reinterpret_cast<float4*>(out + ((size_t)b * S_ + s) * D_ + tid * 4) = o;
}

extern "C" void kernel_launch(void* const* d_in, const int* in_sizes, int n_in,
                              void* d_out, int out_size, void* d_ws, size_t ws_size,
                              hipStream_t stream) {
  const float* X = (const float*)d_in[0];
  // d_in[1] = attn_mask (causal, hardcoded)
  const float* w_gate = (const float*)d_in[2];
  const float* b_gate = (const float*)d_in[3];
  const float* W_qkv = (const float*)d_in[4];
  const float* W_ff = (const float*)d_in[5];
  const float* b_ff = (const float*)d_in[6];
  const float* ln_g = (const float*)d_in[7];
  const float* ln_b = (const float*)d_in[8];
  float* out = (float*)d_out;

  char* ws = (char*)d_ws;
  float* masked_t = (float*)(ws);                           //   524288 B
  float* route_t = (float*)(ws + 524288);                   //   524288 B
  int* seq_ids = (int*)(ws + 1048576);                      //   314368 B
  unsigned short* Qr = (unsigned short*)(ws + 1362944);     // 10485760 B
  unsigned short* Kr = (unsigned short*)(ws + 11848704);    // 10485760 B
  unsigned short* VT = (unsigned short*)(ws + 22334464);    // 10485760 B
  unsigned short* ctx = (unsigned short*)(ws + 32820224);   // 10059776 B
  unsigned short* outb = (unsigned short*)(ws + 42880000);  // 40239104 B
  unsigned short* Xb16 = (unsigned short*)(ws + 83119104);  // 16777216 B
  unsigned short* Wtq = (unsigned short*)(ws + 99896320);   //  6291456 B
  unsigned short* Wtf = (unsigned short*)(ws + 106187776);  //  2097152 B
  // total 108284928 B

  cvt_x_kernel<<<4096, 256, 0, stream>>>(X, Xb16);
  cvt_wqkv_kernel<<<dim3(32, 16), 256, 0, stream>>>(W_qkv, Wtq);
  cvt_wff_kernel<<<dim3(16, 16), 256, 0, stream>>>(W_ff, Wtf);
  gate_kernel<<<2048, 256, 0, stream>>>(X, w_gate, b_gate, masked_t);
  route_kernel<<<(E_ * S_ + 255) / 256, 256, 0, stream>>>(masked_t, route_t);
  select_kernel<<<E_ * B_, 1024, 0, stream>>>(route_t, seq_ids);
  qkv_kernel<<<dim3(10, 64), 512, 0, stream>>>(Xb16, Wtq, seq_ids, Qr, Kr, VT);
  attn_kernel<<<dim3(10, 64), 512, 0, stream>>>(Qr, Kr, VT, ctx);
  for (int b = 0; b < B_; b++) {
    ff_kernel<<<dim3(8, 10, 16), 256, 0, stream>>>(ctx, Wtf, b_ff, outb, b);
    gather_ln_kernel<<<S_, 256, 0, stream>>>(X, outb, seq_ids, ln_g, ln_b, out, b);
  }
}

// Round 6
// 331.733 us; speedup vs baseline: 1.1362x; 1.1362x over previous
//
#include <hip/hip_runtime.h>
#include <math.h>

#define B_ 4
#define S_ 2048
#define D_ 1024
#define E_ 16
#define DH_ 64
#define TOPK_ 8
#define MAXLEN_ 1228
#define MPAD_ 1280
#define CAPF 4.0f
#define EPS_ 1e-6f

typedef __attribute__((ext_vector_type(8))) short bf16x8;
typedef __attribute__((ext_vector_type(4))) float f32x4;

__device__ inline f32x4 mfma16(bf16x8 a, bf16x8 b, f32x4 c) {
  return __builtin_amdgcn_mfma_f32_16x16x32_bf16(a, b, c, 0, 0, 0);
}
__device__ inline float bf2f(unsigned short u) {
  return __uint_as_float(((unsigned)u) << 16);
}
__device__ inline unsigned short f2bf(float f) {
  unsigned u = __float_as_uint(f);
  unsigned r = (u + 0x7FFFu + ((u >> 16) & 1u)) >> 16;
  return (unsigned short)r;
}
__device__ inline ushort4 pk4(float4 v) {
  ushort4 r;
  r.x = f2bf(v.x); r.y = f2bf(v.y); r.z = f2bf(v.z); r.w = f2bf(v.w);
  return r;
}
// XOR-swizzled LDS addressing (byte offsets), 128B rows.
__device__ inline int swz128(int row, int off) { return row * 128 + (off ^ ((row & 7) << 4)); }

// ---------------- one-time converts ----------------
// W_qkv[e][1024 k][192 n] f32 -> Wt[e][192 n][1024 k] bf16
__global__ __launch_bounds__(256) void cvt_wqkv_kernel(
    const float* __restrict__ W, unsigned short* __restrict__ Wt) {
  __shared__ short T[192][40];
  int e = blockIdx.y, k0 = blockIdx.x * 32;
  const float* Wp = W + (size_t)e * D_ * 192 + (size_t)k0 * 192;
  int tid = threadIdx.x;
#pragma unroll
  for (int it = 0; it < 24; it++) {
    int idx = tid + it * 256;  // 0..6143
    int kr = idx / 192, n = idx % 192;
    T[n][kr] = (short)f2bf(Wp[(size_t)kr * 192 + n]);
  }
  __syncthreads();
  unsigned short* Wo = Wt + (size_t)e * 192 * 1024 + k0;
#pragma unroll
  for (int it = 0; it < 3; it++) {
    int idx = tid + it * 256;  // 0..767
    int n = idx >> 2, c = idx & 3;
    bf16x8 v = *reinterpret_cast<bf16x8*>(&T[n][c * 8]);
    *reinterpret_cast<bf16x8*>(Wo + (size_t)n * 1024 + c * 8) = v;
  }
}

// W_ff[e][64 k][1024 n] f32 -> Wt[e][1024 n][64 k] bf16
__global__ __launch_bounds__(256) void cvt_wff_kernel(
    const float* __restrict__ W, unsigned short* __restrict__ Wt) {
  __shared__ short T[64][72];
  int e = blockIdx.y, n0 = blockIdx.x * 64;
  const float* Wp = W + (size_t)e * DH_ * D_;
  int tid = threadIdx.x;
#pragma unroll
  for (int it = 0; it < 16; it++) {
    int idx = tid + it * 256;  // 0..4095
    int k = idx >> 6, n = idx & 63;
    T[n][k] = (short)f2bf(Wp[(size_t)k * D_ + n0 + n]);
  }
  __syncthreads();
  unsigned short* Wo = Wt + (size_t)e * D_ * DH_ + (size_t)n0 * DH_;
#pragma unroll
  for (int it = 0; it < 2; it++) {
    int idx = tid + it * 256;  // 0..511
    int n = idx >> 3, c = idx & 7;
    bf16x8 v = *reinterpret_cast<bf16x8*>(&T[n][c * 8]);
    *reinterpret_cast<bf16x8*>(Wo + (size_t)n * DH_ + c * 8) = v;
  }
}

// --------- Kernel 1: gating -> masked_t[e][b][s]; also emits Xb16 ---------
__global__ __launch_bounds__(256) void gate_kernel(
    const float* __restrict__ X, const float* __restrict__ wg,
    const float* __restrict__ bg, float* __restrict__ masked_t,
    unsigned short* __restrict__ Xb) {
  int token = blockIdx.x * 4 + (threadIdx.x >> 6);  // b*S + s
  int lane = threadIdx.x & 63;
  int b = token / S_, s = token % S_;
  const float* xrow = X + (size_t)token * D_;
  unsigned short* xbrow = Xb + (size_t)token * D_;
  float acc[E_];
#pragma unroll
  for (int e = 0; e < E_; e++) acc[e] = 0.f;
#pragma unroll
  for (int d0 = 0; d0 < D_; d0 += 256) {
    int d = d0 + lane * 4;
    float4 xv = *reinterpret_cast<const float4*>(xrow + d);
    *reinterpret_cast<ushort4*>(xbrow + d) = pk4(xv);  // fused bf16 convert
    const float* w0 = wg + (size_t)d * E_;
#pragma unroll
    for (int e = 0; e < E_; e++)
      acc[e] += xv.x * w0[e] + xv.y * w0[E_ + e] + xv.z * w0[2 * E_ + e] +
                xv.w * w0[3 * E_ + e];
  }
#pragma unroll
  for (int e = 0; e < E_; e++) {
    float v = acc[e];
    for (int off = 32; off; off >>= 1) v += __shfl_xor(v, off);
    acc[e] = v;
  }
  if (lane == 0) {
    float lg[E_], sc[E_], mx = -1e30f;
#pragma unroll
    for (int e = 0; e < E_; e++) {
      lg[e] = acc[e] + bg[e];
      mx = fmaxf(mx, lg[e]);
    }
    float den = 0.f;
#pragma unroll
    for (int e = 0; e < E_; e++) {
      sc[e] = expf(lg[e] - mx);
      den += sc[e];
    }
#pragma unroll
    for (int e = 0; e < E_; e++) sc[e] /= den;
#pragma unroll
    for (int e = 0; e < E_; e++) {
      int rank = 0;
      for (int j = 0; j < E_; j++)
        if (lg[j] > lg[e] || (lg[j] == lg[e] && j < e)) rank++;
      float m = (rank < TOPK_) ? sc[e] : 0.f;
      masked_t[((size_t)e * B_ + b) * S_ + s] = m;
    }
  }
}

// ------- Kernel 3: radix-select top-MAXLEN per (e,b), route fused --------
// Matches lax.top_k on key (value_bits<<32)|(S-1-i): select v>T plus first r
// (ascending index) of v==T, where T is the 1228th largest value.
__global__ __launch_bounds__(256) void select_kernel(
    const float* __restrict__ masked_t, int* __restrict__ seq_ids) {
  __shared__ unsigned vals[S_];
  __shared__ int hist[256];
  __shared__ int wsum[4];
  __shared__ int tsum[4];
  __shared__ unsigned sh_prefix;
  __shared__ int sh_rank;
  int eb = blockIdx.x;
  int e = eb >> 2, b = eb & 3;
  int tid = threadIdx.x;
  int lane = tid & 63, wv = tid >> 6;
  const float* mb0 = masked_t + (size_t)e * B_ * S_;
  for (int i = tid; i < S_; i += 256) {
    float v0 = mb0[i];
    float v1 = mb0[S_ + i];
    float v2 = mb0[2 * S_ + i];
    float v3 = mb0[3 * S_ + i];
    float d = EPS_;
    d += v0; d += v1; d += v2; d += v3;  // same order as old route_kernel
    float mv = mb0[(size_t)b * S_ + i];
    vals[i] = __float_as_uint(mv / d * CAPF);
  }
  if (tid == 0) { sh_prefix = 0u; sh_rank = MAXLEN_; }
  __syncthreads();
  // 4 radix passes (top byte first) to find threshold T
  for (int shift = 24; shift >= 0; shift -= 8) {
    hist[tid] = 0;
    __syncthreads();
    unsigned pfx = sh_prefix;
    unsigned maskhi = (shift == 24) ? 0u : (0xFFFFFFFFu << (shift + 8));
    for (int i = tid; i < S_; i += 256) {
      unsigned v = vals[i];
      if ((v & maskhi) == pfx) atomicAdd(&hist[(v >> shift) & 255], 1);
    }
    __syncthreads();
    int bin = 255 - tid;  // tid 0 -> highest bin
    int h = hist[bin];
    int sc = h;
    for (int off = 1; off < 64; off <<= 1) {
      int n = __shfl_up(sc, off);
      if (lane >= off) sc += n;
    }
    if (lane == 63) wsum[wv] = sc;
    __syncthreads();
    int add = 0;
#pragma unroll
    for (int k = 0; k < 4; k++)
      if (k < wv) add += wsum[k];
    sc += add;  // inclusive count of elems in bins >= bin (within prefix)
    int rank = sh_rank;
    __syncthreads();  // all reads of sh_rank done before the single write
    if (sc - h < rank && rank <= sc) {
      sh_prefix = pfx | ((unsigned)bin << shift);
      sh_rank = rank - (sc - h);
    }
    __syncthreads();
  }
  unsigned T = sh_prefix;
  int r = sh_rank;  // how many of the ==T elems to take (ascending index)
  // flags + two block scans; 8 consecutive elems per thread
  int i0 = tid * 8;
  int eqf[8], gtf[8];
  int eqtot = 0;
#pragma unroll
  for (int k = 0; k < 8; k++) {
    unsigned v = vals[i0 + k];
    eqf[k] = (v == T) ? 1 : 0;
    gtf[k] = (v > T) ? 1 : 0;
    eqtot += eqf[k];
  }
  int esc = eqtot;
  for (int off = 1; off < 64; off <<= 1) {
    int n = __shfl_up(esc, off);
    if (lane >= off) esc += n;
  }
  if (lane == 63) tsum[wv] = esc;
  __syncthreads();
  int eadd = 0;
#pragma unroll
  for (int k = 0; k < 4; k++)
    if (k < wv) eadd += tsum[k];
  int erun = esc - eqtot + eadd;  // exclusive prefix of eq count
  int self_[8];
  int stot = 0;
#pragma unroll
  for (int k = 0; k < 8; k++) {
    int s = gtf[k] | (eqf[k] & (erun < r ? 1 : 0));
    erun += eqf[k];
    self_[k] = s;
    stot += s;
  }
  __syncthreads();  // tsum reuse
  int ssc = stot;
  for (int off = 1; off < 64; off <<= 1) {
    int n = __shfl_up(ssc, off);
    if (lane >= off) ssc += n;
  }
  if (lane == 63) tsum[wv] = ssc;
  __syncthreads();
  int sadd = 0;
#pragma unroll
  for (int k = 0; k < 4; k++)
    if (k < wv) sadd += tsum[k];
  int pos = ssc - stot + sadd;  // exclusive prefix of selected count
  int* outp = seq_ids + (size_t)eb * MAXLEN_;
#pragma unroll
  for (int k = 0; k < 8; k++) {
    if (self_[k]) outp[pos++] = i0 + k;
  }
}

// ---------------- Kernel 4: gathered QKV GEMM (bf16 MFMA) ----------------
// Pipelined: B double-buffered in LDS (1 barrier/K-step), A direct-global
// with register prefetch. Waves: 2 m-frags x 6 n-frags (B-frag reuse x2).
__global__ __launch_bounds__(512) void qkv_kernel(
    const unsigned short* __restrict__ Xb, const unsigned short* __restrict__ Wt,
    const int* __restrict__ seq_ids, unsigned short* __restrict__ Qr,
    unsigned short* __restrict__ Kr, unsigned short* __restrict__ VT) {
  __shared__ __align__(16) char Bt_[2][192 * 128];  // [192 n][64 k] bf16 swz128
  __shared__ int rows[128];
  int eb = blockIdx.y;
  int e = eb >> 2, b = eb & 3;
  int m0 = blockIdx.x * 128;
  int tid = threadIdx.x;
  int w = tid >> 6, l = tid & 63, lr = l & 15, lg = l >> 4;
  int wm = w & 3, wn = w >> 2;
  const int* sid = seq_ids + (size_t)eb * MAXLEN_;
  if (tid < 128) {
    int m = m0 + tid;
    rows[tid] = (m < MAXLEN_) ? sid[m] : 0;
  }
  __syncthreads();
  const unsigned short* Wm = Wt + (size_t)e * 192 * 1024;
  const unsigned short* Xbb = Xb + (size_t)b * S_ * D_;
  const unsigned short* ap0 = Xbb + (size_t)rows[wm * 32 + lr] * D_;
  const unsigned short* ap1 = Xbb + (size_t)rows[wm * 32 + 16 + lr] * D_;
  int s0 = tid, s1 = tid + 512, s2 = tid + 1024;  // staging chunk ids
  f32x4 acc[2][6];
#pragma unroll
  for (int a = 0; a < 2; a++)
#pragma unroll
    for (int j = 0; j < 6; j++) acc[a][j] = (f32x4){0.f, 0.f, 0.f, 0.f};
  // prologue: B tile 0 + A tile 0 into registers
  bf16x8 stg0 = *reinterpret_cast<const bf16x8*>(Wm + (size_t)(s0 >> 3) * 1024 + (s0 & 7) * 8);
  bf16x8 stg1 = *reinterpret_cast<const bf16x8*>(Wm + (size_t)(s1 >> 3) * 1024 + (s1 & 7) * 8);
  bf16x8 stg2 = *reinterpret_cast<const bf16x8*>(Wm + (size_t)(s2 >> 3) * 1024 + (s2 & 7) * 8);
  bf16x8 a00 = *reinterpret_cast<const bf16x8*>(ap0 + lg * 8);
  bf16x8 a01 = *reinterpret_cast<const bf16x8*>(ap0 + 32 + lg * 8);
  bf16x8 a10 = *reinterpret_cast<const bf16x8*>(ap1 + lg * 8);
  bf16x8 a11 = *reinterpret_cast<const bf16x8*>(ap1 + 32 + lg * 8);
  for (int t = 0; t < 16; t++) {
    char* buf = Bt_[t & 1];
    // write tile t (loaded during iter t-1) to LDS
    *reinterpret_cast<bf16x8*>(buf + swz128(s0 >> 3, (s0 & 7) * 16)) = stg0;
    *reinterpret_cast<bf16x8*>(buf + swz128(s1 >> 3, (s1 & 7) * 16)) = stg1;
    *reinterpret_cast<bf16x8*>(buf + swz128(s2 >> 3, (s2 & 7) * 16)) = stg2;
    // issue global loads for tile t+1 (in flight across the barrier)
    bf16x8 n0, n1, n2, b00, b01, b10, b11;
    if (t < 15) {
      int kn = (t + 1) * 64;
      n0 = *reinterpret_cast<const bf16x8*>(Wm + (size_t)(s0 >> 3) * 1024 + kn + (s0 & 7) * 8);
      n1 = *reinterpret_cast<const bf16x8*>(Wm + (size_t)(s1 >> 3) * 1024 + kn + (s1 & 7) * 8);
      n2 = *reinterpret_cast<const bf16x8*>(Wm + (size_t)(s2 >> 3) * 1024 + kn + (s2 & 7) * 8);
      b00 = *reinterpret_cast<const bf16x8*>(ap0 + kn + lg * 8);
      b01 = *reinterpret_cast<const bf16x8*>(ap0 + kn + 32 + lg * 8);
      b10 = *reinterpret_cast<const bf16x8*>(ap1 + kn + lg * 8);
      b11 = *reinterpret_cast<const bf16x8*>(ap1 + kn + 32 + lg * 8);
    }
    __syncthreads();
#pragma unroll
    for (int j = 0; j < 6; j++) {
      int nr = (wn * 6 + j) * 16 + lr;
      bf16x8 bf0 = *reinterpret_cast<bf16x8*>(buf + swz128(nr, lg * 16));
      bf16x8 bf1 = *reinterpret_cast<bf16x8*>(buf + swz128(nr, 64 + lg * 16));
      acc[0][j] = mfma16(a00, bf0, acc[0][j]);
      acc[1][j] = mfma16(a10, bf0, acc[1][j]);
      acc[0][j] = mfma16(a01, bf1, acc[0][j]);
      acc[1][j] = mfma16(a11, bf1, acc[1][j]);
    }
    if (t < 15) {
      stg0 = n0; stg1 = n1; stg2 = n2;
      a00 = b00; a01 = b01; a10 = b10; a11 = b11;
    }
  }
  unsigned short* Qe = Qr + (size_t)eb * MPAD_ * 64;
  unsigned short* Ke = Kr + (size_t)eb * MPAD_ * 64;
  unsigned short* Ve = VT + (size_t)eb * 64 * MPAD_;
#pragma unroll
  for (int a = 0; a < 2; a++) {
    int mb = m0 + wm * 32 + a * 16 + lg * 4;
#pragma unroll
    for (int j = 0; j < 6; j++) {
      int nbg = wn * 6 + j;
      if (nbg < 4) {
#pragma unroll
        for (int i = 0; i < 4; i++) {
          int m = mb + i;
          float v = (m < MAXLEN_) ? acc[a][j][i] * 0.125f : 0.f;
          Qe[(size_t)m * 64 + nbg * 16 + lr] = f2bf(v);
        }
      } else if (nbg < 8) {
#pragma unroll
        for (int i = 0; i < 4; i++) {
          int m = mb + i;
          float v = (m < MAXLEN_) ? acc[a][j][i] : 0.f;
          Ke[(size_t)m * 64 + (nbg - 4) * 16 + lr] = f2bf(v);
        }
      } else {
        ushort4 pv;
        pv.x = (mb + 0 < MAXLEN_) ? f2bf(acc[a][j][0]) : (unsigned short)0;
        pv.y = (mb + 1 < MAXLEN_) ? f2bf(acc[a][j][1]) : (unsigned short)0;
        pv.z = (mb + 2 < MAXLEN_) ? f2bf(acc[a][j][2]) : (unsigned short)0;
        pv.w = (mb + 3 < MAXLEN_) ? f2bf(acc[a][j][3]) : (unsigned short)0;
        *reinterpret_cast<ushort4*>(Ve + (size_t)((nbg - 8) * 16 + lr) * MPAD_ + mb) = pv;
      }
    }
  }
}

// ------------- Kernel 5: flash attention, bf16 MFMA, per (e,b) -------------
// q-tile 128 (8 waves x 16 q cols), k-tile 64. S^T = K.Q^T; O^T = V^T.P^T.
__global__ __launch_bounds__(512) void attn_kernel(
    const unsigned short* __restrict__ Qr, const unsigned short* __restrict__ Kr,
    const unsigned short* __restrict__ VT, unsigned short* __restrict__ ctx) {
  __shared__ __align__(16) char Ks_[64 * 128];      // [64 k][64 d] swz128
  __shared__ __align__(16) char Vt_[64 * 128];      // [64 dv][64 k] swz128
  __shared__ __align__(16) char Pl_[8 * 16 * 128];  // per-wave [16 q][64 k]
  int qb = 9 - blockIdx.x;  // longest first
  int eb = blockIdx.y;
  const unsigned short* Qe = Qr + (size_t)eb * MPAD_ * 64;
  const unsigned short* Ke = Kr + (size_t)eb * MPAD_ * 64;
  const unsigned short* Ve = VT + (size_t)eb * 64 * MPAD_;
  int tid = threadIdx.x;
  int w = tid >> 6, l = tid & 63, lr = l & 15, lg = l >> 4;
  int gq = qb * 128 + w * 16 + lr;  // this lane's q column
  bf16x8 qf[2];
  qf[0] = *reinterpret_cast<const bf16x8*>(Qe + (size_t)gq * 64 + lg * 8);
  qf[1] = *reinterpret_cast<const bf16x8*>(Qe + (size_t)gq * 64 + 32 + lg * 8);
  f32x4 acc[4];
#pragma unroll
  for (int db = 0; db < 4; db++) acc[db] = (f32x4){0.f, 0.f, 0.f, 0.f};
  float mrow = -1e30f, lsum = 0.f;
  char* Pw = Pl_ + w * 2048;
  int srow = tid >> 3, sc = (tid & 7) * 8;  // staging coords
  int ndiag = 2 * qb, ktmax = 2 * qb + 1;
  for (int kt = 0; kt <= ktmax; kt++) {
    int k0 = kt * 64;
    {
      bf16x8 kv = *reinterpret_cast<const bf16x8*>(Ke + (size_t)(k0 + srow) * 64 + sc);
      *reinterpret_cast<bf16x8*>(Ks_ + swz128(srow, sc * 2)) = kv;
      bf16x8 vv = *reinterpret_cast<const bf16x8*>(Ve + (size_t)srow * MPAD_ + k0 + sc);
      *reinterpret_cast<bf16x8*>(Vt_ + swz128(srow, sc * 2)) = vv;
    }
    __syncthreads();
    f32x4 sac[4];
#pragma unroll
    for (int kb = 0; kb < 4; kb++) {
      sac[kb] = (f32x4){0.f, 0.f, 0.f, 0.f};
#pragma unroll
      for (int ds = 0; ds < 2; ds++) {
        bf16x8 kf = *reinterpret_cast<bf16x8*>(Ks_ + swz128(kb * 16 + lr, ds * 64 + lg * 16));
        sac[kb] = mfma16(kf, qf[ds], sac[kb]);
      }
    }
    float p[16];
    float tmax = -1e30f;
    if (kt >= ndiag) {  // diagonal tiles: causal + OOB mask
#pragma unroll
      for (int kb = 0; kb < 4; kb++) {
#pragma unroll
        for (int i = 0; i < 4; i++) {
          int k = k0 + kb * 16 + lg * 4 + i;
          float s = sac[kb][i];
          if (k > gq || k >= MAXLEN_) s = -1e9f;
          p[kb * 4 + i] = s;
          tmax = fmaxf(tmax, s);
        }
      }
    } else {
#pragma unroll
      for (int kb = 0; kb < 4; kb++) {
#pragma unroll
        for (int i = 0; i < 4; i++) {
          float s = sac[kb][i];
          p[kb * 4 + i] = s;
          tmax = fmaxf(tmax, s);
        }
      }
    }
    tmax = fmaxf(tmax, __shfl_xor(tmax, 16));
    tmax = fmaxf(tmax, __shfl_xor(tmax, 32));
    if (!__all(tmax <= mrow + 8.f)) {  // T13 defer-rescale
      float mnew = fmaxf(mrow, tmax);
      float corr = __expf(mrow - mnew);
      lsum *= corr;
#pragma unroll
      for (int db = 0; db < 4; db++) acc[db] = acc[db] * corr;
      mrow = mnew;
    }
    float psum = 0.f;
#pragma unroll
    for (int j = 0; j < 16; j++) {
      p[j] = __expf(p[j] - mrow);
      psum += p[j];
    }
    psum += __shfl_xor(psum, 16);
    psum += __shfl_xor(psum, 32);
    lsum += psum;
#pragma unroll
    for (int kb = 0; kb < 4; kb++) {
#pragma unroll
      for (int ip = 0; ip < 2; ip++) {
        unsigned u = (unsigned)f2bf(p[kb * 4 + ip * 2]) |
                     ((unsigned)f2bf(p[kb * 4 + ip * 2 + 1]) << 16);
        int k = kb * 16 + lg * 4 + ip * 2;
        *reinterpret_cast<unsigned*>(Pw + swz128(lr, k * 2)) = u;
      }
    }
    bf16x8 pf[2];
#pragma unroll
    for (int ks = 0; ks < 2; ks++)
      pf[ks] = *reinterpret_cast<bf16x8*>(Pw + swz128(lr, ks * 64 + lg * 16));
#pragma unroll
    for (int db = 0; db < 4; db++) {
#pragma unroll
      for (int ks = 0; ks < 2; ks++) {
        bf16x8 vf = *reinterpret_cast<bf16x8*>(Vt_ + swz128(db * 16 + lr, ks * 64 + lg * 16));
        acc[db] = mfma16(vf, pf[ks], acc[db]);
      }
    }
    __syncthreads();
  }
  if (gq < MAXLEN_) {
    float inv = 1.f / lsum;
    unsigned short* op = ctx + ((size_t)eb * MAXLEN_ + gq) * DH_;
#pragma unroll
    for (int db = 0; db < 4; db++) {
      ushort4 pv;
      pv.x = f2bf(acc[db][0] * inv);
      pv.y = f2bf(acc[db][1] * inv);
      pv.z = f2bf(acc[db][2] * inv);
      pv.w = f2bf(acc[db][3] * inv);
      *reinterpret_cast<ushort4*>(op + db * 16 + lg * 4) = pv;
    }
  }
}

// ------- Kernel 6: FF GEMM (bf16 MFMA) -> outb[e][m][:] for batch b -------
__global__ __launch_bounds__(256) void ff_kernel(
    const unsigned short* __restrict__ ctx, const unsigned short* __restrict__ Wtff,
    const float* __restrict__ bff, unsigned short* __restrict__ outb, int b) {
  __shared__ __align__(16) char As_[128 * 128];  // [128 m][64 k] bf16 swz128
  __shared__ __align__(16) char Bt_[128 * 128];  // [128 n][64 k] bf16 swz128
  int e = blockIdx.z;
  int m0 = blockIdx.y * 128, n0 = blockIdx.x * 128;
  int tid = threadIdx.x;
  int w = tid >> 6, l = tid & 63, lr = l & 15, lg = l >> 4;
  const unsigned short* A = ctx + (size_t)(e * B_ + b) * MAXLEN_ * DH_;
  const unsigned short* Wm = Wtff + (size_t)e * D_ * DH_;
#pragma unroll
  for (int it = 0; it < 8; it++) {
    int idx = tid + it * 256;  // 0..2047
    int row = idx >> 4, kq = (idx & 15) * 4;
    int gm = m0 + row;
    if (gm >= MAXLEN_) gm = MAXLEN_ - 1;
    ushort4 av = *reinterpret_cast<const ushort4*>(A + (size_t)gm * DH_ + kq);
    *reinterpret_cast<ushort4*>(As_ + swz128(row, kq * 2)) = av;
  }
#pragma unroll
  for (int it = 0; it < 4; it++) {
    int idx = tid + it * 256;  // 0..1023
    int row = idx >> 3, c = idx & 7;
    bf16x8 v = *reinterpret_cast<const bf16x8*>(Wm + (size_t)(n0 + row) * DH_ + c * 8);
    *reinterpret_cast<bf16x8*>(Bt_ + swz128(row, c * 16)) = v;
  }
  __syncthreads();
  int wm = w >> 1, wn = w & 1;
  f32x4 acc[4][4];
#pragma unroll
  for (int mb = 0; mb < 4; mb++)
#pragma unroll
    for (int nb = 0; nb < 4; nb++) acc[mb][nb] = (f32x4){0.f, 0.f, 0.f, 0.f};
#pragma unroll
  for (int ks = 0; ks < 2; ks++) {
    bf16x8 af[4], bfr[4];
#pragma unroll
    for (int mb = 0; mb < 4; mb++)
      af[mb] = *reinterpret_cast<bf16x8*>(As_ + swz128(wm * 64 + mb * 16 + lr, ks * 64 + lg * 16));
#pragma unroll
    for (int nb = 0; nb < 4; nb++)
      bfr[nb] = *reinterpret_cast<bf16x8*>(Bt_ + swz128(wn * 64 + nb * 16 + lr, ks * 64 + lg * 16));
#pragma unroll
    for (int mb = 0; mb < 4; mb++)
#pragma unroll
      for (int nb = 0; nb < 4; nb++)
        acc[mb][nb] = mfma16(af[mb], bfr[nb], acc[mb][nb]);
  }
  float bias[4];
#pragma unroll
  for (int nb = 0; nb < 4; nb++)
    bias[nb] = bff[(size_t)e * D_ + n0 + wn * 64 + nb * 16 + lr];
#pragma unroll
  for (int mb = 0; mb < 4; mb++) {
#pragma unroll
    for (int i = 0; i < 4; i++) {
      int m = m0 + wm * 64 + mb * 16 + lg * 4 + i;
      if (m < MAXLEN_) {
        unsigned short* orow = outb + ((size_t)e * MAXLEN_ + m) * D_ + n0 + wn * 64;
#pragma unroll
        for (int nb = 0; nb < 4; nb++)
          orow[nb * 16 + lr] = f2bf(acc[mb][nb][i] + bias[nb]);
      }
    }
  }
}

// ------- Kernel 7: per-token gather (binary search) + residual + LayerNorm -
__global__ __launch_bounds__(256) void gather_ln_kernel(
    const float* __restrict__ X, const unsigned short* __restrict__ outb,
    const int* __restrict__ seq_ids, const float* __restrict__ gamma,
    const float* __restrict__ beta, float* __restrict__ out, int b) {
  __shared__ int ms[E_];
  __shared__ float w1[4], w2[4];
  int s = blockIdx.x;
  int tid = threadIdx.x;
  if (tid < E_) {
    const int* sid = seq_ids + ((size_t)tid * B_ + b) * MAXLEN_;
    int lo = 0, hi = MAXLEN_;
    while (lo < hi) {
      int mid = (lo + hi) >> 1;
      if (sid[mid] < s) lo = mid + 1; else hi = mid;
    }
    ms[tid] = (lo < MAXLEN_ && sid[lo] == s) ? lo : -1;
  }
  __syncthreads();
  const float* xr = X + ((size_t)b * S_ + s) * D_;
  float4 xv = *reinterpret_cast<const float4*>(xr + tid * 4);
  float v[4] = {xv.x, xv.y, xv.z, xv.w};
#pragma unroll
  for (int e = 0; e < E_; e++) {
    int m = ms[e];
    if (m >= 0) {
      const unsigned short* orow = outb + ((size_t)e * MAXLEN_ + m) * D_;
      ushort4 u = *reinterpret_cast<const ushort4*>(orow + tid * 4);
      v[0] += bf2f(u.x); v[1] += bf2f(u.y); v[2] += bf2f(u.z); v[3] += bf2f(u.w);
    }
  }
  float s1 = v[0] + v[1] + v[2] + v[3];
  float s2 = v[0] * v[0] + v[1] * v[1] + v[2] * v[2] + v[3] * v[3];
  for (int off = 32; off; off >>= 1) {
    s1 += __shfl_xor(s1, off);
    s2 += __shfl_xor(s2, off);
  }
  int wv = tid >> 6;
  if ((tid & 63) == 0) { w1[wv] = s1; w2[wv] = s2; }
  __syncthreads();
  s1 = w1[0] + w1[1] + w1[2] + w1[3];
  s2 = w2[0] + w2[1] + w2[2] + w2[3];
  float mu = s1 * (1.f / D_);
  float var = s2 * (1.f / D_) - mu * mu;
  float inv = rsqrtf(var + 1e-5f);
  float4 g = *reinterpret_cast<const float4*>(gamma + tid * 4);
  float4 be = *reinterpret_cast<const float4*>(beta + tid * 4);
  float4 o;
  o.x = (v[0] - mu) * inv * g.x + be.x;
  o.y = (v[1] - mu) * inv * g.y + be.y;
  o.z = (v[2] - mu) * inv * g.z + be.z;
  o.w = (v[3] - mu) * inv * g.w + be.w;
  *reinterpret_cast<float4*>(out + ((size_t)b * S_ + s) * D_ + tid * 4) = o;
}

extern "C" void kernel_launch(void* const* d_in, const int* in_sizes, int n_in,
                              void* d_out, int out_size, void* d_ws, size_t ws_size,
                              hipStream_t stream) {
  const float* X = (const float*)d_in[0];
  // d_in[1] = attn_mask (causal, hardcoded)
  const float* w_gate = (const float*)d_in[2];
  const float* b_gate = (const float*)d_in[3];
  const float* W_qkv = (const float*)d_in[4];
  const float* W_ff = (const float*)d_in[5];
  const float* b_ff = (const float*)d_in[6];
  const float* ln_g = (const float*)d_in[7];
  const float* ln_b = (const float*)d_in[8];
  float* out = (float*)d_out;

  char* ws = (char*)d_ws;
  float* masked_t = (float*)(ws);                           //   524288 B
  int* seq_ids = (int*)(ws + 1048576);                      //   314368 B
  unsigned short* Qr = (unsigned short*)(ws + 1362944);     // 10485760 B
  unsigned short* Kr = (unsigned short*)(ws + 11848704);    // 10485760 B
  unsigned short* VT = (unsigned short*)(ws + 22334464);    // 10485760 B
  unsigned short* ctx = (unsigned short*)(ws + 32820224);   // 10059776 B
  unsigned short* outb = (unsigned short*)(ws + 42880000);  // 40239104 B
  unsigned short* Xb16 = (unsigned short*)(ws + 83119104);  // 16777216 B
  unsigned short* Wtq = (unsigned short*)(ws + 99896320);   //  6291456 B
  unsigned short* Wtf = (unsigned short*)(ws + 106187776);  //  2097152 B
  // total 108284928 B

  cvt_wqkv_kernel<<<dim3(32, 16), 256, 0, stream>>>(W_qkv, Wtq);
  cvt_wff_kernel<<<dim3(16, 16), 256, 0, stream>>>(W_ff, Wtf);
  gate_kernel<<<2048, 256, 0, stream>>>(X, w_gate, b_gate, masked_t, Xb16);
  select_kernel<<<E_ * B_, 256, 0, stream>>>(masked_t, seq_ids);
  qkv_kernel<<<dim3(10, 64), 512, 0, stream>>>(Xb16, Wtq, seq_ids, Qr, Kr, VT);
  attn_kernel<<<dim3(10, 64), 512, 0, stream>>>(Qr, Kr, VT, ctx);
  for (int b = 0; b < B_; b++) {
    ff_kernel<<<dim3(8, 10, 16), 256, 0, stream>>>(ctx, Wtf, b_ff, outb, b);
    gather_ln_kernel<<<S_, 256, 0, stream>>>(X, outb, seq_ids, ln_g, ln_b, out, b);
  }
}

// Round 7
// 271.636 us; speedup vs baseline: 1.3876x; 1.2212x over previous
//
#include <hip/hip_runtime.h>
#include <math.h>

#define B_ 4
#define S_ 2048
#define D_ 1024
#define E_ 16
#define DH_ 64
#define TOPK_ 8
#define MAXLEN_ 1228
#define MPAD_ 1280
#define CAPF 4.0f
#define EPS_ 1e-6f

typedef __attribute__((ext_vector_type(8))) short bf16x8;
typedef __attribute__((ext_vector_type(4))) float f32x4;

__device__ inline f32x4 mfma16(bf16x8 a, bf16x8 b, f32x4 c) {
  return __builtin_amdgcn_mfma_f32_16x16x32_bf16(a, b, c, 0, 0, 0);
}
__device__ inline float bf2f(unsigned short u) {
  return __uint_as_float(((unsigned)u) << 16);
}
__device__ inline unsigned short f2bf(float f) {
  unsigned u = __float_as_uint(f);
  unsigned r = (u + 0x7FFFu + ((u >> 16) & 1u)) >> 16;
  return (unsigned short)r;
}
__device__ inline ushort4 pk4(float4 v) {
  ushort4 r;
  r.x = f2bf(v.x); r.y = f2bf(v.y); r.z = f2bf(v.z); r.w = f2bf(v.w);
  return r;
}
// XOR-swizzled LDS addressing (byte offsets), 128B rows.
__device__ inline int swz128(int row, int off) { return row * 128 + (off ^ ((row & 7) << 4)); }

// ---------------- one-time converts ----------------
// W_qkv[e][1024 k][192 n] f32 -> Wt[e][192 n][1024 k] bf16
__global__ __launch_bounds__(256) void cvt_wqkv_kernel(
    const float* __restrict__ W, unsigned short* __restrict__ Wt) {
  __shared__ short T[192][40];
  int e = blockIdx.y, k0 = blockIdx.x * 32;
  const float* Wp = W + (size_t)e * D_ * 192 + (size_t)k0 * 192;
  int tid = threadIdx.x;
#pragma unroll
  for (int it = 0; it < 24; it++) {
    int idx = tid + it * 256;  // 0..6143
    int kr = idx / 192, n = idx % 192;
    T[n][kr] = (short)f2bf(Wp[(size_t)kr * 192 + n]);
  }
  __syncthreads();
  unsigned short* Wo = Wt + (size_t)e * 192 * 1024 + k0;
#pragma unroll
  for (int it = 0; it < 3; it++) {
    int idx = tid + it * 256;  // 0..767
    int n = idx >> 2, c = idx & 3;
    bf16x8 v = *reinterpret_cast<bf16x8*>(&T[n][c * 8]);
    *reinterpret_cast<bf16x8*>(Wo + (size_t)n * 1024 + c * 8) = v;
  }
}

// W_ff[e][64 k][1024 n] f32 -> Wt[e][1024 n][64 k] bf16
__global__ __launch_bounds__(256) void cvt_wff_kernel(
    const float* __restrict__ W, unsigned short* __restrict__ Wt) {
  __shared__ short T[64][72];
  int e = blockIdx.y, n0 = blockIdx.x * 64;
  const float* Wp = W + (size_t)e * DH_ * D_;
  int tid = threadIdx.x;
#pragma unroll
  for (int it = 0; it < 16; it++) {
    int idx = tid + it * 256;  // 0..4095
    int k = idx >> 6, n = idx & 63;
    T[n][k] = (short)f2bf(Wp[(size_t)k * D_ + n0 + n]);
  }
  __syncthreads();
  unsigned short* Wo = Wt + (size_t)e * D_ * DH_ + (size_t)n0 * DH_;
#pragma unroll
  for (int it = 0; it < 2; it++) {
    int idx = tid + it * 256;  // 0..511
    int n = idx >> 3, c = idx & 7;
    bf16x8 v = *reinterpret_cast<bf16x8*>(&T[n][c * 8]);
    *reinterpret_cast<bf16x8*>(Wo + (size_t)n * DH_ + c * 8) = v;
  }
}

// wg[1024 d][16 e] f32 -> wgT[16 e][1024 d] f32 (64 KB, one-time)
__global__ __launch_bounds__(256) void cvt_wgt_kernel(
    const float* __restrict__ wg, float* __restrict__ wgT) {
  int idx = blockIdx.x * 256 + threadIdx.x;  // 0..16383
  int e = idx >> 10, d = idx & 1023;
  wgT[idx] = wg[(size_t)d * E_ + e];
}

// --------- Kernel 1: gating -> masked_t[e][b][s]; also emits Xb16 ---------
__global__ __launch_bounds__(256) void gate_kernel(
    const float* __restrict__ X, const float* __restrict__ wgT,
    const float* __restrict__ bg, float* __restrict__ masked_t,
    unsigned short* __restrict__ Xb) {
  int token = blockIdx.x * 4 + (threadIdx.x >> 6);  // b*S + s
  int lane = threadIdx.x & 63;
  int b = token / S_, s = token % S_;
  const float* xrow = X + (size_t)token * D_;
  unsigned short* xbrow = Xb + (size_t)token * D_;
  float acc[E_];
#pragma unroll
  for (int e = 0; e < E_; e++) acc[e] = 0.f;
#pragma unroll
  for (int d0 = 0; d0 < D_; d0 += 256) {
    int d = d0 + lane * 4;
    float4 xv = *reinterpret_cast<const float4*>(xrow + d);
    *reinterpret_cast<ushort4*>(xbrow + d) = pk4(xv);  // fused bf16 convert
#pragma unroll
    for (int e = 0; e < E_; e++) {
      float4 wv = *reinterpret_cast<const float4*>(wgT + (size_t)e * D_ + d);
      acc[e] += xv.x * wv.x + xv.y * wv.y + xv.z * wv.z + xv.w * wv.w;
    }
  }
#pragma unroll
  for (int e = 0; e < E_; e++) {
    float v = acc[e];
    for (int off = 32; off; off >>= 1) v += __shfl_xor(v, off);
    acc[e] = v;
  }
  if (lane == 0) {
    float lg[E_], sc[E_], mx = -1e30f;
#pragma unroll
    for (int e = 0; e < E_; e++) {
      lg[e] = acc[e] + bg[e];
      mx = fmaxf(mx, lg[e]);
    }
    float den = 0.f;
#pragma unroll
    for (int e = 0; e < E_; e++) {
      sc[e] = expf(lg[e] - mx);
      den += sc[e];
    }
#pragma unroll
    for (int e = 0; e < E_; e++) sc[e] /= den;
#pragma unroll
    for (int e = 0; e < E_; e++) {
      int rank = 0;
      for (int j = 0; j < E_; j++)
        if (lg[j] > lg[e] || (lg[j] == lg[e] && j < e)) rank++;
      float m = (rank < TOPK_) ? sc[e] : 0.f;
      masked_t[((size_t)e * B_ + b) * S_ + s] = m;
    }
  }
}

// ------- Kernel 3: radix-select top-MAXLEN per (e,b), route fused --------
__global__ __launch_bounds__(256) void select_kernel(
    const float* __restrict__ masked_t, int* __restrict__ seq_ids) {
  __shared__ unsigned vals[S_];
  __shared__ int hist[256];
  __shared__ int wsum[4];
  __shared__ int tsum[4];
  __shared__ unsigned sh_prefix;
  __shared__ int sh_rank;
  int eb = blockIdx.x;
  int e = eb >> 2, b = eb & 3;
  int tid = threadIdx.x;
  int lane = tid & 63, wv = tid >> 6;
  const float* mb0 = masked_t + (size_t)e * B_ * S_;
  for (int i = tid; i < S_; i += 256) {
    float v0 = mb0[i];
    float v1 = mb0[S_ + i];
    float v2 = mb0[2 * S_ + i];
    float v3 = mb0[3 * S_ + i];
    float d = EPS_;
    d += v0; d += v1; d += v2; d += v3;  // same order as route_kernel
    float mv = mb0[(size_t)b * S_ + i];
    vals[i] = __float_as_uint(mv / d * CAPF);
  }
  if (tid == 0) { sh_prefix = 0u; sh_rank = MAXLEN_; }
  __syncthreads();
  for (int shift = 24; shift >= 0; shift -= 8) {
    hist[tid] = 0;
    __syncthreads();
    unsigned pfx = sh_prefix;
    unsigned maskhi = (shift == 24) ? 0u : (0xFFFFFFFFu << (shift + 8));
    for (int i = tid; i < S_; i += 256) {
      unsigned v = vals[i];
      if ((v & maskhi) == pfx) atomicAdd(&hist[(v >> shift) & 255], 1);
    }
    __syncthreads();
    int bin = 255 - tid;
    int h = hist[bin];
    int sc = h;
    for (int off = 1; off < 64; off <<= 1) {
      int n = __shfl_up(sc, off);
      if (lane >= off) sc += n;
    }
    if (lane == 63) wsum[wv] = sc;
    __syncthreads();
    int add = 0;
#pragma unroll
    for (int k = 0; k < 4; k++)
      if (k < wv) add += wsum[k];
    sc += add;
    int rank = sh_rank;
    __syncthreads();
    if (sc - h < rank && rank <= sc) {
      sh_prefix = pfx | ((unsigned)bin << shift);
      sh_rank = rank - (sc - h);
    }
    __syncthreads();
  }
  unsigned T = sh_prefix;
  int r = sh_rank;
  int i0 = tid * 8;
  int eqf[8], gtf[8];
  int eqtot = 0;
#pragma unroll
  for (int k = 0; k < 8; k++) {
    unsigned v = vals[i0 + k];
    eqf[k] = (v == T) ? 1 : 0;
    gtf[k] = (v > T) ? 1 : 0;
    eqtot += eqf[k];
  }
  int esc = eqtot;
  for (int off = 1; off < 64; off <<= 1) {
    int n = __shfl_up(esc, off);
    if (lane >= off) esc += n;
  }
  if (lane == 63) tsum[wv] = esc;
  __syncthreads();
  int eadd = 0;
#pragma unroll
  for (int k = 0; k < 4; k++)
    if (k < wv) eadd += tsum[k];
  int erun = esc - eqtot + eadd;
  int self_[8];
  int stot = 0;
#pragma unroll
  for (int k = 0; k < 8; k++) {
    int s = gtf[k] | (eqf[k] & (erun < r ? 1 : 0));
    erun += eqf[k];
    self_[k] = s;
    stot += s;
  }
  __syncthreads();
  int ssc = stot;
  for (int off = 1; off < 64; off <<= 1) {
    int n = __shfl_up(ssc, off);
    if (lane >= off) ssc += n;
  }
  if (lane == 63) tsum[wv] = ssc;
  __syncthreads();
  int sadd = 0;
#pragma unroll
  for (int k = 0; k < 4; k++)
    if (k < wv) sadd += tsum[k];
  int pos = ssc - stot + sadd;
  int* outp = seq_ids + (size_t)eb * MAXLEN_;
#pragma unroll
  for (int k = 0; k < 8; k++) {
    if (self_[k]) outp[pos++] = i0 + k;
  }
}

// ---------------- Kernel 4: gathered QKV GEMM (bf16 MFMA) ----------------
__global__ __launch_bounds__(512) void qkv_kernel(
    const unsigned short* __restrict__ Xb, const unsigned short* __restrict__ Wt,
    const int* __restrict__ seq_ids, unsigned short* __restrict__ Qr,
    unsigned short* __restrict__ Kr, unsigned short* __restrict__ VT) {
  __shared__ __align__(16) char Bt_[2][192 * 128];  // [192 n][64 k] bf16 swz128
  __shared__ int rows[128];
  int eb = blockIdx.y;
  int e = eb >> 2, b = eb & 3;
  int m0 = blockIdx.x * 128;
  int tid = threadIdx.x;
  int w = tid >> 6, l = tid & 63, lr = l & 15, lg = l >> 4;
  int wm = w & 3, wn = w >> 2;
  const int* sid = seq_ids + (size_t)eb * MAXLEN_;
  if (tid < 128) {
    int m = m0 + tid;
    rows[tid] = (m < MAXLEN_) ? sid[m] : 0;
  }
  __syncthreads();
  const unsigned short* Wm = Wt + (size_t)e * 192 * 1024;
  const unsigned short* Xbb = Xb + (size_t)b * S_ * D_;
  const unsigned short* ap0 = Xbb + (size_t)rows[wm * 32 + lr] * D_;
  const unsigned short* ap1 = Xbb + (size_t)rows[wm * 32 + 16 + lr] * D_;
  int s0 = tid, s1 = tid + 512, s2 = tid + 1024;
  f32x4 acc[2][6];
#pragma unroll
  for (int a = 0; a < 2; a++)
#pragma unroll
    for (int j = 0; j < 6; j++) acc[a][j] = (f32x4){0.f, 0.f, 0.f, 0.f};
  bf16x8 stg0 = *reinterpret_cast<const bf16x8*>(Wm + (size_t)(s0 >> 3) * 1024 + (s0 & 7) * 8);
  bf16x8 stg1 = *reinterpret_cast<const bf16x8*>(Wm + (size_t)(s1 >> 3) * 1024 + (s1 & 7) * 8);
  bf16x8 stg2 = *reinterpret_cast<const bf16x8*>(Wm + (size_t)(s2 >> 3) * 1024 + (s2 & 7) * 8);
  bf16x8 a00 = *reinterpret_cast<const bf16x8*>(ap0 + lg * 8);
  bf16x8 a01 = *reinterpret_cast<const bf16x8*>(ap0 + 32 + lg * 8);
  bf16x8 a10 = *reinterpret_cast<const bf16x8*>(ap1 + lg * 8);
  bf16x8 a11 = *reinterpret_cast<const bf16x8*>(ap1 + 32 + lg * 8);
  for (int t = 0; t < 16; t++) {
    char* buf = Bt_[t & 1];
    *reinterpret_cast<bf16x8*>(buf + swz128(s0 >> 3, (s0 & 7) * 16)) = stg0;
    *reinterpret_cast<bf16x8*>(buf + swz128(s1 >> 3, (s1 & 7) * 16)) = stg1;
    *reinterpret_cast<bf16x8*>(buf + swz128(s2 >> 3, (s2 & 7) * 16)) = stg2;
    bf16x8 n0, n1, n2, b00, b01, b10, b11;
    if (t < 15) {
      int kn = (t + 1) * 64;
      n0 = *reinterpret_cast<const bf16x8*>(Wm + (size_t)(s0 >> 3) * 1024 + kn + (s0 & 7) * 8);
      n1 = *reinterpret_cast<const bf16x8*>(Wm + (size_t)(s1 >> 3) * 1024 + kn + (s1 & 7) * 8);
      n2 = *reinterpret_cast<const bf16x8*>(Wm + (size_t)(s2 >> 3) * 1024 + kn + (s2 & 7) * 8);
      b00 = *reinterpret_cast<const bf16x8*>(ap0 + kn + lg * 8);
      b01 = *reinterpret_cast<const bf16x8*>(ap0 + kn + 32 + lg * 8);
      b10 = *reinterpret_cast<const bf16x8*>(ap1 + kn + lg * 8);
      b11 = *reinterpret_cast<const bf16x8*>(ap1 + kn + 32 + lg * 8);
    }
    __syncthreads();
#pragma unroll
    for (int j = 0; j < 6; j++) {
      int nr = (wn * 6 + j) * 16 + lr;
      bf16x8 bf0 = *reinterpret_cast<bf16x8*>(buf + swz128(nr, lg * 16));
      bf16x8 bf1 = *reinterpret_cast<bf16x8*>(buf + swz128(nr, 64 + lg * 16));
      acc[0][j] = mfma16(a00, bf0, acc[0][j]);
      acc[1][j] = mfma16(a10, bf0, acc[1][j]);
      acc[0][j] = mfma16(a01, bf1, acc[0][j]);
      acc[1][j] = mfma16(a11, bf1, acc[1][j]);
    }
    if (t < 15) {
      stg0 = n0; stg1 = n1; stg2 = n2;
      a00 = b00; a01 = b01; a10 = b10; a11 = b11;
    }
  }
  unsigned short* Qe = Qr + (size_t)eb * MPAD_ * 64;
  unsigned short* Ke = Kr + (size_t)eb * MPAD_ * 64;
  unsigned short* Ve = VT + (size_t)eb * 64 * MPAD_;
#pragma unroll
  for (int a = 0; a < 2; a++) {
    int mb = m0 + wm * 32 + a * 16 + lg * 4;
#pragma unroll
    for (int j = 0; j < 6; j++) {
      int nbg = wn * 6 + j;
      if (nbg < 4) {
#pragma unroll
        for (int i = 0; i < 4; i++) {
          int m = mb + i;
          float v = (m < MAXLEN_) ? acc[a][j][i] * 0.125f : 0.f;
          Qe[(size_t)m * 64 + nbg * 16 + lr] = f2bf(v);
        }
      } else if (nbg < 8) {
#pragma unroll
        for (int i = 0; i < 4; i++) {
          int m = mb + i;
          float v = (m < MAXLEN_) ? acc[a][j][i] : 0.f;
          Ke[(size_t)m * 64 + (nbg - 4) * 16 + lr] = f2bf(v);
        }
      } else {
        ushort4 pv;
        pv.x = (mb + 0 < MAXLEN_) ? f2bf(acc[a][j][0]) : (unsigned short)0;
        pv.y = (mb + 1 < MAXLEN_) ? f2bf(acc[a][j][1]) : (unsigned short)0;
        pv.z = (mb + 2 < MAXLEN_) ? f2bf(acc[a][j][2]) : (unsigned short)0;
        pv.w = (mb + 3 < MAXLEN_) ? f2bf(acc[a][j][3]) : (unsigned short)0;
        *reinterpret_cast<ushort4*>(Ve + (size_t)((nbg - 8) * 16 + lr) * MPAD_ + mb) = pv;
      }
    }
  }
}

// ------------- Kernel 5: flash attention, bf16 MFMA, per (e,b) -------------
__global__ __launch_bounds__(512) void attn_kernel(
    const unsigned short* __restrict__ Qr, const unsigned short* __restrict__ Kr,
    const unsigned short* __restrict__ VT, unsigned short* __restrict__ ctx) {
  __shared__ __align__(16) char Ks_[64 * 128];      // [64 k][64 d] swz128
  __shared__ __align__(16) char Vt_[64 * 128];      // [64 dv][64 k] swz128
  __shared__ __align__(16) char Pl_[8 * 16 * 128];  // per-wave [16 q][64 k]
  int qb = 9 - blockIdx.x;  // longest first
  int eb = blockIdx.y;
  const unsigned short* Qe = Qr + (size_t)eb * MPAD_ * 64;
  const unsigned short* Ke = Kr + (size_t)eb * MPAD_ * 64;
  const unsigned short* Ve = VT + (size_t)eb * 64 * MPAD_;
  int tid = threadIdx.x;
  int w = tid >> 6, l = tid & 63, lr = l & 15, lg = l >> 4;
  int gq = qb * 128 + w * 16 + lr;
  bf16x8 qf[2];
  qf[0] = *reinterpret_cast<const bf16x8*>(Qe + (size_t)gq * 64 + lg * 8);
  qf[1] = *reinterpret_cast<const bf16x8*>(Qe + (size_t)gq * 64 + 32 + lg * 8);
  f32x4 acc[4];
#pragma unroll
  for (int db = 0; db < 4; db++) acc[db] = (f32x4){0.f, 0.f, 0.f, 0.f};
  float mrow = -1e30f, lsum = 0.f;
  char* Pw = Pl_ + w * 2048;
  int srow = tid >> 3, sc = (tid & 7) * 8;
  int ndiag = 2 * qb, ktmax = 2 * qb + 1;
  for (int kt = 0; kt <= ktmax; kt++) {
    int k0 = kt * 64;
    {
      bf16x8 kv = *reinterpret_cast<const bf16x8*>(Ke + (size_t)(k0 + srow) * 64 + sc);
      *reinterpret_cast<bf16x8*>(Ks_ + swz128(srow, sc * 2)) = kv;
      bf16x8 vv = *reinterpret_cast<const bf16x8*>(Ve + (size_t)srow * MPAD_ + k0 + sc);
      *reinterpret_cast<bf16x8*>(Vt_ + swz128(srow, sc * 2)) = vv;
    }
    __syncthreads();
    f32x4 sac[4];
#pragma unroll
    for (int kb = 0; kb < 4; kb++) {
      sac[kb] = (f32x4){0.f, 0.f, 0.f, 0.f};
#pragma unroll
      for (int ds = 0; ds < 2; ds++) {
        bf16x8 kf = *reinterpret_cast<bf16x8*>(Ks_ + swz128(kb * 16 + lr, ds * 64 + lg * 16));
        sac[kb] = mfma16(kf, qf[ds], sac[kb]);
      }
    }
    float p[16];
    float tmax = -1e30f;
    if (kt >= ndiag) {
#pragma unroll
      for (int kb = 0; kb < 4; kb++) {
#pragma unroll
        for (int i = 0; i < 4; i++) {
          int k = k0 + kb * 16 + lg * 4 + i;
          float s = sac[kb][i];
          if (k > gq || k >= MAXLEN_) s = -1e9f;
          p[kb * 4 + i] = s;
          tmax = fmaxf(tmax, s);
        }
      }
    } else {
#pragma unroll
      for (int kb = 0; kb < 4; kb++) {
#pragma unroll
        for (int i = 0; i < 4; i++) {
          float s = sac[kb][i];
          p[kb * 4 + i] = s;
          tmax = fmaxf(tmax, s);
        }
      }
    }
    tmax = fmaxf(tmax, __shfl_xor(tmax, 16));
    tmax = fmaxf(tmax, __shfl_xor(tmax, 32));
    if (!__all(tmax <= mrow + 8.f)) {
      float mnew = fmaxf(mrow, tmax);
      float corr = __expf(mrow - mnew);
      lsum *= corr;
#pragma unroll
      for (int db = 0; db < 4; db++) acc[db] = acc[db] * corr;
      mrow = mnew;
    }
    float psum = 0.f;
#pragma unroll
    for (int j = 0; j < 16; j++) {
      p[j] = __expf(p[j] - mrow);
      psum += p[j];
    }
    psum += __shfl_xor(psum, 16);
    psum += __shfl_xor(psum, 32);
    lsum += psum;
#pragma unroll
    for (int kb = 0; kb < 4; kb++) {
#pragma unroll
      for (int ip = 0; ip < 2; ip++) {
        unsigned u = (unsigned)f2bf(p[kb * 4 + ip * 2]) |
                     ((unsigned)f2bf(p[kb * 4 + ip * 2 + 1]) << 16);
        int k = kb * 16 + lg * 4 + ip * 2;
        *reinterpret_cast<unsigned*>(Pw + swz128(lr, k * 2)) = u;
      }
    }
    bf16x8 pf[2];
#pragma unroll
    for (int ks = 0; ks < 2; ks++)
      pf[ks] = *reinterpret_cast<bf16x8*>(Pw + swz128(lr, ks * 64 + lg * 16));
#pragma unroll
    for (int db = 0; db < 4; db++) {
#pragma unroll
      for (int ks = 0; ks < 2; ks++) {
        bf16x8 vf = *reinterpret_cast<bf16x8*>(Vt_ + swz128(db * 16 + lr, ks * 64 + lg * 16));
        acc[db] = mfma16(vf, pf[ks], acc[db]);
      }
    }
    __syncthreads();
  }
  if (gq < MAXLEN_) {
    float inv = 1.f / lsum;
    unsigned short* op = ctx + ((size_t)eb * MAXLEN_ + gq) * DH_;
#pragma unroll
    for (int db = 0; db < 4; db++) {
      ushort4 pv;
      pv.x = f2bf(acc[db][0] * inv);
      pv.y = f2bf(acc[db][1] * inv);
      pv.z = f2bf(acc[db][2] * inv);
      pv.w = f2bf(acc[db][3] * inv);
      *reinterpret_cast<ushort4*>(op + db * 16 + lg * 4) = pv;
    }
  }
}

// ---- Kernel 6: FF GEMM (bf16 MFMA) -> outb[(e*nb+bi)][m][:] for nb batches -
__global__ __launch_bounds__(256) void ff_kernel(
    const unsigned short* __restrict__ ctx, const unsigned short* __restrict__ Wtff,
    const float* __restrict__ bff, unsigned short* __restrict__ outb,
    int b0, int nb) {
  __shared__ __align__(16) char As_[128 * 128];
  __shared__ __align__(16) char Bt_[128 * 128];
  int z = blockIdx.z;
  int e = z / nb, bi = z % nb, b = b0 + bi;
  int m0 = blockIdx.y * 128, n0 = blockIdx.x * 128;
  int tid = threadIdx.x;
  int w = tid >> 6, l = tid & 63, lr = l & 15, lg = l >> 4;
  const unsigned short* A = ctx + (size_t)(e * B_ + b) * MAXLEN_ * DH_;
  const unsigned short* Wm = Wtff + (size_t)e * D_ * DH_;
#pragma unroll
  for (int it = 0; it < 8; it++) {
    int idx = tid + it * 256;
    int row = idx >> 4, kq = (idx & 15) * 4;
    int gm = m0 + row;
    if (gm >= MAXLEN_) gm = MAXLEN_ - 1;
    ushort4 av = *reinterpret_cast<const ushort4*>(A + (size_t)gm * DH_ + kq);
    *reinterpret_cast<ushort4*>(As_ + swz128(row, kq * 2)) = av;
  }
#pragma unroll
  for (int it = 0; it < 4; it++) {
    int idx = tid + it * 256;
    int row = idx >> 3, c = idx & 7;
    bf16x8 v = *reinterpret_cast<const bf16x8*>(Wm + (size_t)(n0 + row) * DH_ + c * 8);
    *reinterpret_cast<bf16x8*>(Bt_ + swz128(row, c * 16)) = v;
  }
  __syncthreads();
  int wm = w >> 1, wn = w & 1;
  f32x4 acc[4][4];
#pragma unroll
  for (int mb = 0; mb < 4; mb++)
#pragma unroll
    for (int nb2 = 0; nb2 < 4; nb2++) acc[mb][nb2] = (f32x4){0.f, 0.f, 0.f, 0.f};
#pragma unroll
  for (int ks = 0; ks < 2; ks++) {
    bf16x8 af[4], bfr[4];
#pragma unroll
    for (int mb = 0; mb < 4; mb++)
      af[mb] = *reinterpret_cast<bf16x8*>(As_ + swz128(wm * 64 + mb * 16 + lr, ks * 64 + lg * 16));
#pragma unroll
    for (int nb2 = 0; nb2 < 4; nb2++)
      bfr[nb2] = *reinterpret_cast<bf16x8*>(Bt_ + swz128(wn * 64 + nb2 * 16 + lr, ks * 64 + lg * 16));
#pragma unroll
    for (int mb = 0; mb < 4; mb++)
#pragma unroll
      for (int nb2 = 0; nb2 < 4; nb2++)
        acc[mb][nb2] = mfma16(af[mb], bfr[nb2], acc[mb][nb2]);
  }
  float bias[4];
#pragma unroll
  for (int nb2 = 0; nb2 < 4; nb2++)
    bias[nb2] = bff[(size_t)e * D_ + n0 + wn * 64 + nb2 * 16 + lr];
  unsigned short* obase = outb + (size_t)(e * nb + bi) * MAXLEN_ * D_;
#pragma unroll
  for (int mb = 0; mb < 4; mb++) {
#pragma unroll
    for (int i = 0; i < 4; i++) {
      int m = m0 + wm * 64 + mb * 16 + lg * 4 + i;
      if (m < MAXLEN_) {
        unsigned short* orow = obase + (size_t)m * D_ + n0 + wn * 64;
#pragma unroll
        for (int nb2 = 0; nb2 < 4; nb2++)
          orow[nb2 * 16 + lr] = f2bf(acc[mb][nb2][i] + bias[nb2]);
      }
    }
  }
}

// ------- Kernel 7: per-token gather (binary search) + residual + LayerNorm -
__global__ __launch_bounds__(256) void gather_ln_kernel(
    const float* __restrict__ X, const unsigned short* __restrict__ outb,
    const int* __restrict__ seq_ids, const float* __restrict__ gamma,
    const float* __restrict__ beta, float* __restrict__ out, int b0, int nb) {
  __shared__ int ms[E_];
  __shared__ float w1[4], w2[4];
  int bi = blockIdx.x / S_;
  int s = blockIdx.x % S_;
  int b = b0 + bi;
  int tid = threadIdx.x;
  if (tid < E_) {
    const int* sid = seq_ids + ((size_t)tid * B_ + b) * MAXLEN_;
    int lo = 0, hi = MAXLEN_;
    while (lo < hi) {
      int mid = (lo + hi) >> 1;
      if (sid[mid] < s) lo = mid + 1; else hi = mid;
    }
    ms[tid] = (lo < MAXLEN_ && sid[lo] == s) ? lo : -1;
  }
  __syncthreads();
  const float* xr = X + ((size_t)b * S_ + s) * D_;
  float4 xv = *reinterpret_cast<const float4*>(xr + tid * 4);
  float v[4] = {xv.x, xv.y, xv.z, xv.w};
#pragma unroll
  for (int e = 0; e < E_; e++) {
    int m = ms[e];
    if (m >= 0) {
      const unsigned short* orow = outb + (size_t)(e * nb + bi) * MAXLEN_ * D_ + (size_t)m * D_;
      ushort4 u = *reinterpret_cast<const ushort4*>(orow + tid * 4);
      v[0] += bf2f(u.x); v[1] += bf2f(u.y); v[2] += bf2f(u.z); v[3] += bf2f(u.w);
    }
  }
  float s1 = v[0] + v[1] + v[2] + v[3];
  float s2 = v[0] * v[0] + v[1] * v[1] + v[2] * v[2] + v[3] * v[3];
  for (int off = 32; off; off >>= 1) {
    s1 += __shfl_xor(s1, off);
    s2 += __shfl_xor(s2, off);
  }
  int wv = tid >> 6;
  if ((tid & 63) == 0) { w1[wv] = s1; w2[wv] = s2; }
  __syncthreads();
  s1 = w1[0] + w1[1] + w1[2] + w1[3];
  s2 = w2[0] + w2[1] + w2[2] + w2[3];
  float mu = s1 * (1.f / D_);
  float var = s2 * (1.f / D_) - mu * mu;
  float inv = rsqrtf(var + 1e-5f);
  float4 g = *reinterpret_cast<const float4*>(gamma + tid * 4);
  float4 be = *reinterpret_cast<const float4*>(beta + tid * 4);
  float4 o;
  o.x = (v[0] - mu) * inv * g.x + be.x;
  o.y = (v[1] - mu) * inv * g.y + be.y;
  o.z = (v[2] - mu) * inv * g.z + be.z;
  o.w = (v[3] - mu) * inv * g.w + be.w;
  *reinterpret_cast<float4*>(out + ((size_t)b * S_ + s) * D_ + tid * 4) = o;
}

extern "C" void kernel_launch(void* const* d_in, const int* in_sizes, int n_in,
                              void* d_out, int out_size, void* d_ws, size_t ws_size,
                              hipStream_t stream) {
  const float* X = (const float*)d_in[0];
  // d_in[1] = attn_mask (causal, hardcoded)
  const float* w_gate = (const float*)d_in[2];
  const float* b_gate = (const float*)d_in[3];
  const float* W_qkv = (const float*)d_in[4];
  const float* W_ff = (const float*)d_in[5];
  const float* b_ff = (const float*)d_in[6];
  const float* ln_g = (const float*)d_in[7];
  const float* ln_b = (const float*)d_in[8];
  float* out = (float*)d_out;

  char* ws = (char*)d_ws;
  float* masked_t = (float*)(ws);                           //   524288 B
  int* seq_ids = (int*)(ws + 1048576);                      //   314368 B
  unsigned short* Qr = (unsigned short*)(ws + 1362944);     // 10485760 B
  unsigned short* Kr = (unsigned short*)(ws + 11848704);    // 10485760 B
  unsigned short* VT = (unsigned short*)(ws + 22334464);    // 10485760 B
  unsigned short* ctx = (unsigned short*)(ws + 32820224);   // 10059776 B
  unsigned short* Xb16 = (unsigned short*)(ws + 42880000);  // 16777216 B
  unsigned short* Wtq = (unsigned short*)(ws + 59657216);   //  6291456 B
  unsigned short* Wtf = (unsigned short*)(ws + 65948672);   //  2097152 B
  float* wgT = (float*)(ws + 68045824);                     //    65536 B
  unsigned short* outb = (unsigned short*)(ws + 68111360);  // nb*40239104 B

  const size_t OUTB1 = (size_t)E_ * MAXLEN_ * D_ * 2;  // 40239104
  int nb = 1;
  if (ws_size >= 68111360ull + 4 * OUTB1) nb = 4;
  else if (ws_size >= 68111360ull + 2 * OUTB1) nb = 2;

  cvt_wqkv_kernel<<<dim3(32, 16), 256, 0, stream>>>(W_qkv, Wtq);
  cvt_wff_kernel<<<dim3(16, 16), 256, 0, stream>>>(W_ff, Wtf);
  cvt_wgt_kernel<<<64, 256, 0, stream>>>(w_gate, wgT);
  gate_kernel<<<2048, 256, 0, stream>>>(X, wgT, b_gate, masked_t, Xb16);
  select_kernel<<<E_ * B_, 256, 0, stream>>>(masked_t, seq_ids);
  qkv_kernel<<<dim3(10, 64), 512, 0, stream>>>(Xb16, Wtq, seq_ids, Qr, Kr, VT);
  attn_kernel<<<dim3(10, 64), 512, 0, stream>>>(Qr, Kr, VT, ctx);
  for (int b0 = 0; b0 < B_; b0 += nb) {
    ff_kernel<<<dim3(8, 10, E_ * nb), 256, 0, stream>>>(ctx, Wtf, b_ff, outb, b0, nb);
    gather_ln_kernel<<<nb * S_, 256, 0, stream>>>(X, outb, seq_ids, ln_g, ln_b, out, b0, nb);
  }
}

// Round 8
// 261.403 us; speedup vs baseline: 1.4419x; 1.0391x over previous
//
#include <hip/hip_runtime.h>
#include <math.h>

#define B_ 4
#define S_ 2048
#define D_ 1024
#define E_ 16
#define DH_ 64
#define TOPK_ 8
#define MAXLEN_ 1228
#define MPAD_ 1280
#define CAPF 4.0f
#define EPS_ 1e-6f

typedef __attribute__((ext_vector_type(8))) short bf16x8;
typedef __attribute__((ext_vector_type(4))) float f32x4;

__device__ inline f32x4 mfma16(bf16x8 a, bf16x8 b, f32x4 c) {
  return __builtin_amdgcn_mfma_f32_16x16x32_bf16(a, b, c, 0, 0, 0);
}
__device__ inline float bf2f(unsigned short u) {
  return __uint_as_float(((unsigned)u) << 16);
}
__device__ inline unsigned short f2bf(float f) {
  unsigned u = __float_as_uint(f);
  unsigned r = (u + 0x7FFFu + ((u >> 16) & 1u)) >> 16;
  return (unsigned short)r;
}
__device__ inline ushort4 pk4(float4 v) {
  ushort4 r;
  r.x = f2bf(v.x); r.y = f2bf(v.y); r.z = f2bf(v.z); r.w = f2bf(v.w);
  return r;
}
// XOR-swizzled LDS addressing (byte offsets), 128B rows.
__device__ inline int swz128(int row, int off) { return row * 128 + (off ^ ((row & 7) << 4)); }

// ---------------- one-time converts ----------------
// W_qkv[e][1024 k][192 n] f32 -> Wt[e][192 n][1024 k] bf16
__global__ __launch_bounds__(256) void cvt_wqkv_kernel(
    const float* __restrict__ W, unsigned short* __restrict__ Wt) {
  __shared__ short T[192][40];
  int e = blockIdx.y, k0 = blockIdx.x * 32;
  const float* Wp = W + (size_t)e * D_ * 192 + (size_t)k0 * 192;
  int tid = threadIdx.x;
#pragma unroll
  for (int it = 0; it < 24; it++) {
    int idx = tid + it * 256;  // 0..6143
    int kr = idx / 192, n = idx % 192;
    T[n][kr] = (short)f2bf(Wp[(size_t)kr * 192 + n]);
  }
  __syncthreads();
  unsigned short* Wo = Wt + (size_t)e * 192 * 1024 + k0;
#pragma unroll
  for (int it = 0; it < 3; it++) {
    int idx = tid + it * 256;  // 0..767
    int n = idx >> 2, c = idx & 3;
    bf16x8 v = *reinterpret_cast<bf16x8*>(&T[n][c * 8]);
    *reinterpret_cast<bf16x8*>(Wo + (size_t)n * 1024 + c * 8) = v;
  }
}

// W_ff[e][64 k][1024 n] f32 -> Wt[e][1024 n][64 k] bf16
__global__ __launch_bounds__(256) void cvt_wff_kernel(
    const float* __restrict__ W, unsigned short* __restrict__ Wt) {
  __shared__ short T[64][72];
  int e = blockIdx.y, n0 = blockIdx.x * 64;
  const float* Wp = W + (size_t)e * DH_ * D_;
  int tid = threadIdx.x;
#pragma unroll
  for (int it = 0; it < 16; it++) {
    int idx = tid + it * 256;  // 0..4095
    int k = idx >> 6, n = idx & 63;
    T[n][k] = (short)f2bf(Wp[(size_t)k * D_ + n0 + n]);
  }
  __syncthreads();
  unsigned short* Wo = Wt + (size_t)e * D_ * DH_ + (size_t)n0 * DH_;
#pragma unroll
  for (int it = 0; it < 2; it++) {
    int idx = tid + it * 256;  // 0..511
    int n = idx >> 3, c = idx & 7;
    bf16x8 v = *reinterpret_cast<bf16x8*>(&T[n][c * 8]);
    *reinterpret_cast<bf16x8*>(Wo + (size_t)n * DH_ + c * 8) = v;
  }
}

// wg[1024 d][16 e] f32 -> wgT[16 e][1024 d] f32 (64 KB, one-time)
__global__ __launch_bounds__(256) void cvt_wgt_kernel(
    const float* __restrict__ wg, float* __restrict__ wgT) {
  int idx = blockIdx.x * 256 + threadIdx.x;  // 0..16383
  int e = idx >> 10, d = idx & 1023;
  wgT[idx] = wg[(size_t)d * E_ + e];
}

// bff[16 e][1024 n] f32 -> bffT[1024 n][32 k] bf16 (k=e for e<16, else 0)
__global__ __launch_bounds__(256) void cvt_bff_kernel(
    const float* __restrict__ bff, unsigned short* __restrict__ bffT) {
  int n = blockIdx.x * 256 + threadIdx.x;  // 0..1023
  unsigned short* o = bffT + (size_t)n * 32;
#pragma unroll
  for (int e = 0; e < E_; e++) o[e] = f2bf(bff[(size_t)e * D_ + n]);
#pragma unroll
  for (int e = E_; e < 32; e++) o[e] = 0;
}

// --------- Kernel 1: gating -> masked_t[e][b][s]; also emits Xb16 ---------
__global__ __launch_bounds__(256) void gate_kernel(
    const float* __restrict__ X, const float* __restrict__ wgT,
    const float* __restrict__ bg, float* __restrict__ masked_t,
    unsigned short* __restrict__ Xb) {
  int token = blockIdx.x * 4 + (threadIdx.x >> 6);  // b*S + s
  int lane = threadIdx.x & 63;
  int b = token / S_, s = token % S_;
  const float* xrow = X + (size_t)token * D_;
  unsigned short* xbrow = Xb + (size_t)token * D_;
  float acc[E_];
#pragma unroll
  for (int e = 0; e < E_; e++) acc[e] = 0.f;
#pragma unroll
  for (int d0 = 0; d0 < D_; d0 += 256) {
    int d = d0 + lane * 4;
    float4 xv = *reinterpret_cast<const float4*>(xrow + d);
    *reinterpret_cast<ushort4*>(xbrow + d) = pk4(xv);  // fused bf16 convert
#pragma unroll
    for (int e = 0; e < E_; e++) {
      float4 wv = *reinterpret_cast<const float4*>(wgT + (size_t)e * D_ + d);
      acc[e] += xv.x * wv.x + xv.y * wv.y + xv.z * wv.z + xv.w * wv.w;
    }
  }
#pragma unroll
  for (int e = 0; e < E_; e++) {
    float v = acc[e];
    for (int off = 32; off; off >>= 1) v += __shfl_xor(v, off);
    acc[e] = v;
  }
  if (lane == 0) {
    float lg[E_], sc[E_], mx = -1e30f;
#pragma unroll
    for (int e = 0; e < E_; e++) {
      lg[e] = acc[e] + bg[e];
      mx = fmaxf(mx, lg[e]);
    }
    float den = 0.f;
#pragma unroll
    for (int e = 0; e < E_; e++) {
      sc[e] = expf(lg[e] - mx);
      den += sc[e];
    }
#pragma unroll
    for (int e = 0; e < E_; e++) sc[e] /= den;
#pragma unroll
    for (int e = 0; e < E_; e++) {
      int rank = 0;
      for (int j = 0; j < E_; j++)
        if (lg[j] > lg[e] || (lg[j] == lg[e] && j < e)) rank++;
      float m = (rank < TOPK_) ? sc[e] : 0.f;
      masked_t[((size_t)e * B_ + b) * S_ + s] = m;
    }
  }
}

// ------- Kernel 3: radix-select top-MAXLEN per (e,b), route fused --------
__global__ __launch_bounds__(256) void select_kernel(
    const float* __restrict__ masked_t, int* __restrict__ seq_ids) {
  __shared__ unsigned vals[S_];
  __shared__ int hist[256];
  __shared__ int wsum[4];
  __shared__ int tsum[4];
  __shared__ unsigned sh_prefix;
  __shared__ int sh_rank;
  int eb = blockIdx.x;
  int e = eb >> 2, b = eb & 3;
  int tid = threadIdx.x;
  int lane = tid & 63, wv = tid >> 6;
  const float* mb0 = masked_t + (size_t)e * B_ * S_;
  for (int i = tid; i < S_; i += 256) {
    float v0 = mb0[i];
    float v1 = mb0[S_ + i];
    float v2 = mb0[2 * S_ + i];
    float v3 = mb0[3 * S_ + i];
    float d = EPS_;
    d += v0; d += v1; d += v2; d += v3;  // same order as route_kernel
    float mv = mb0[(size_t)b * S_ + i];
    vals[i] = __float_as_uint(mv / d * CAPF);
  }
  if (tid == 0) { sh_prefix = 0u; sh_rank = MAXLEN_; }
  __syncthreads();
  for (int shift = 24; shift >= 0; shift -= 8) {
    hist[tid] = 0;
    __syncthreads();
    unsigned pfx = sh_prefix;
    unsigned maskhi = (shift == 24) ? 0u : (0xFFFFFFFFu << (shift + 8));
    for (int i = tid; i < S_; i += 256) {
      unsigned v = vals[i];
      if ((v & maskhi) == pfx) atomicAdd(&hist[(v >> shift) & 255], 1);
    }
    __syncthreads();
    int bin = 255 - tid;
    int h = hist[bin];
    int sc = h;
    for (int off = 1; off < 64; off <<= 1) {
      int n = __shfl_up(sc, off);
      if (lane >= off) sc += n;
    }
    if (lane == 63) wsum[wv] = sc;
    __syncthreads();
    int add = 0;
#pragma unroll
    for (int k = 0; k < 4; k++)
      if (k < wv) add += wsum[k];
    sc += add;
    int rank = sh_rank;
    __syncthreads();
    if (sc - h < rank && rank <= sc) {
      sh_prefix = pfx | ((unsigned)bin << shift);
      sh_rank = rank - (sc - h);
    }
    __syncthreads();
  }
  unsigned T = sh_prefix;
  int r = sh_rank;
  int i0 = tid * 8;
  int eqf[8], gtf[8];
  int eqtot = 0;
#pragma unroll
  for (int k = 0; k < 8; k++) {
    unsigned v = vals[i0 + k];
    eqf[k] = (v == T) ? 1 : 0;
    gtf[k] = (v > T) ? 1 : 0;
    eqtot += eqf[k];
  }
  int esc = eqtot;
  for (int off = 1; off < 64; off <<= 1) {
    int n = __shfl_up(esc, off);
    if (lane >= off) esc += n;
  }
  if (lane == 63) tsum[wv] = esc;
  __syncthreads();
  int eadd = 0;
#pragma unroll
  for (int k = 0; k < 4; k++)
    if (k < wv) eadd += tsum[k];
  int erun = esc - eqtot + eadd;
  int self_[8];
  int stot = 0;
#pragma unroll
  for (int k = 0; k < 8; k++) {
    int s = gtf[k] | (eqf[k] & (erun < r ? 1 : 0));
    erun += eqf[k];
    self_[k] = s;
    stot += s;
  }
  __syncthreads();
  int ssc = stot;
  for (int off = 1; off < 64; off <<= 1) {
    int n = __shfl_up(ssc, off);
    if (lane >= off) ssc += n;
  }
  if (lane == 63) tsum[wv] = ssc;
  __syncthreads();
  int sadd = 0;
#pragma unroll
  for (int k = 0; k < 4; k++)
    if (k < wv) sadd += tsum[k];
  int pos = ssc - stot + sadd;
  int* outp = seq_ids + (size_t)eb * MAXLEN_;
#pragma unroll
  for (int k = 0; k < 8; k++) {
    if (self_[k]) outp[pos++] = i0 + k;
  }
}

// --------- Kernel 3b: inverse map inv[eb][s] = m (or -1) ---------
__global__ __launch_bounds__(256) void inv_kernel(
    const int* __restrict__ seq_ids, int* __restrict__ inv) {
  int eb = blockIdx.x;
  int tid = threadIdx.x;
  int* ip = inv + (size_t)eb * S_;
  for (int i = tid; i < S_; i += 256) ip[i] = -1;
  __syncthreads();
  const int* sid = seq_ids + (size_t)eb * MAXLEN_;
  for (int m = tid; m < MAXLEN_; m += 256) ip[sid[m]] = m;
}

// ---------------- Kernel 4: gathered QKV GEMM (bf16 MFMA) ----------------
__global__ __launch_bounds__(512) void qkv_kernel(
    const unsigned short* __restrict__ Xb, const unsigned short* __restrict__ Wt,
    const int* __restrict__ seq_ids, unsigned short* __restrict__ Qr,
    unsigned short* __restrict__ Kr, unsigned short* __restrict__ VT) {
  __shared__ __align__(16) char Bt_[2][192 * 128];  // [192 n][64 k] bf16 swz128
  __shared__ int rows[128];
  int eb = blockIdx.y;
  int e = eb >> 2, b = eb & 3;
  int m0 = blockIdx.x * 128;
  int tid = threadIdx.x;
  int w = tid >> 6, l = tid & 63, lr = l & 15, lg = l >> 4;
  int wm = w & 3, wn = w >> 2;
  const int* sid = seq_ids + (size_t)eb * MAXLEN_;
  if (tid < 128) {
    int m = m0 + tid;
    rows[tid] = (m < MAXLEN_) ? sid[m] : 0;
  }
  __syncthreads();
  const unsigned short* Wm = Wt + (size_t)e * 192 * 1024;
  const unsigned short* Xbb = Xb + (size_t)b * S_ * D_;
  const unsigned short* ap0 = Xbb + (size_t)rows[wm * 32 + lr] * D_;
  const unsigned short* ap1 = Xbb + (size_t)rows[wm * 32 + 16 + lr] * D_;
  int s0 = tid, s1 = tid + 512, s2 = tid + 1024;
  f32x4 acc[2][6];
#pragma unroll
  for (int a = 0; a < 2; a++)
#pragma unroll
    for (int j = 0; j < 6; j++) acc[a][j] = (f32x4){0.f, 0.f, 0.f, 0.f};
  bf16x8 stg0 = *reinterpret_cast<const bf16x8*>(Wm + (size_t)(s0 >> 3) * 1024 + (s0 & 7) * 8);
  bf16x8 stg1 = *reinterpret_cast<const bf16x8*>(Wm + (size_t)(s1 >> 3) * 1024 + (s1 & 7) * 8);
  bf16x8 stg2 = *reinterpret_cast<const bf16x8*>(Wm + (size_t)(s2 >> 3) * 1024 + (s2 & 7) * 8);
  bf16x8 a00 = *reinterpret_cast<const bf16x8*>(ap0 + lg * 8);
  bf16x8 a01 = *reinterpret_cast<const bf16x8*>(ap0 + 32 + lg * 8);
  bf16x8 a10 = *reinterpret_cast<const bf16x8*>(ap1 + lg * 8);
  bf16x8 a11 = *reinterpret_cast<const bf16x8*>(ap1 + 32 + lg * 8);
  for (int t = 0; t < 16; t++) {
    char* buf = Bt_[t & 1];
    *reinterpret_cast<bf16x8*>(buf + swz128(s0 >> 3, (s0 & 7) * 16)) = stg0;
    *reinterpret_cast<bf16x8*>(buf + swz128(s1 >> 3, (s1 & 7) * 16)) = stg1;
    *reinterpret_cast<bf16x8*>(buf + swz128(s2 >> 3, (s2 & 7) * 16)) = stg2;
    bf16x8 n0, n1, n2, b00, b01, b10, b11;
    if (t < 15) {
      int kn = (t + 1) * 64;
      n0 = *reinterpret_cast<const bf16x8*>(Wm + (size_t)(s0 >> 3) * 1024 + kn + (s0 & 7) * 8);
      n1 = *reinterpret_cast<const bf16x8*>(Wm + (size_t)(s1 >> 3) * 1024 + kn + (s1 & 7) * 8);
      n2 = *reinterpret_cast<const bf16x8*>(Wm + (size_t)(s2 >> 3) * 1024 + kn + (s2 & 7) * 8);
      b00 = *reinterpret_cast<const bf16x8*>(ap0 + kn + lg * 8);
      b01 = *reinterpret_cast<const bf16x8*>(ap0 + kn + 32 + lg * 8);
      b10 = *reinterpret_cast<const bf16x8*>(ap1 + kn + lg * 8);
      b11 = *reinterpret_cast<const bf16x8*>(ap1 + kn + 32 + lg * 8);
    }
    __syncthreads();
#pragma unroll
    for (int j = 0; j < 6; j++) {
      int nr = (wn * 6 + j) * 16 + lr;
      bf16x8 bf0 = *reinterpret_cast<bf16x8*>(buf + swz128(nr, lg * 16));
      bf16x8 bf1 = *reinterpret_cast<bf16x8*>(buf + swz128(nr, 64 + lg * 16));
      acc[0][j] = mfma16(a00, bf0, acc[0][j]);
      acc[1][j] = mfma16(a10, bf0, acc[1][j]);
      acc[0][j] = mfma16(a01, bf1, acc[0][j]);
      acc[1][j] = mfma16(a11, bf1, acc[1][j]);
    }
    if (t < 15) {
      stg0 = n0; stg1 = n1; stg2 = n2;
      a00 = b00; a01 = b01; a10 = b10; a11 = b11;
    }
  }
  unsigned short* Qe = Qr + (size_t)eb * MPAD_ * 64;
  unsigned short* Ke = Kr + (size_t)eb * MPAD_ * 64;
  unsigned short* Ve = VT + (size_t)eb * 64 * MPAD_;
#pragma unroll
  for (int a = 0; a < 2; a++) {
    int mb = m0 + wm * 32 + a * 16 + lg * 4;
#pragma unroll
    for (int j = 0; j < 6; j++) {
      int nbg = wn * 6 + j;
      if (nbg < 4) {
#pragma unroll
        for (int i = 0; i < 4; i++) {
          int m = mb + i;
          float v = (m < MAXLEN_) ? acc[a][j][i] * 0.125f : 0.f;
          Qe[(size_t)m * 64 + nbg * 16 + lr] = f2bf(v);
        }
      } else if (nbg < 8) {
#pragma unroll
        for (int i = 0; i < 4; i++) {
          int m = mb + i;
          float v = (m < MAXLEN_) ? acc[a][j][i] : 0.f;
          Ke[(size_t)m * 64 + (nbg - 4) * 16 + lr] = f2bf(v);
        }
      } else {
        ushort4 pv;
        pv.x = (mb + 0 < MAXLEN_) ? f2bf(acc[a][j][0]) : (unsigned short)0;
        pv.y = (mb + 1 < MAXLEN_) ? f2bf(acc[a][j][1]) : (unsigned short)0;
        pv.z = (mb + 2 < MAXLEN_) ? f2bf(acc[a][j][2]) : (unsigned short)0;
        pv.w = (mb + 3 < MAXLEN_) ? f2bf(acc[a][j][3]) : (unsigned short)0;
        *reinterpret_cast<ushort4*>(Ve + (size_t)((nbg - 8) * 16 + lr) * MPAD_ + mb) = pv;
      }
    }
  }
}

// ------------- Kernel 5: flash attention, bf16 MFMA, per (e,b) -------------
__global__ __launch_bounds__(512) void attn_kernel(
    const unsigned short* __restrict__ Qr, const unsigned short* __restrict__ Kr,
    const unsigned short* __restrict__ VT, unsigned short* __restrict__ ctx) {
  __shared__ __align__(16) char Ks_[64 * 128];      // [64 k][64 d] swz128
  __shared__ __align__(16) char Vt_[64 * 128];      // [64 dv][64 k] swz128
  __shared__ __align__(16) char Pl_[8 * 16 * 128];  // per-wave [16 q][64 k]
  int qb = 9 - blockIdx.x;  // longest first
  int eb = blockIdx.y;
  const unsigned short* Qe = Qr + (size_t)eb * MPAD_ * 64;
  const unsigned short* Ke = Kr + (size_t)eb * MPAD_ * 64;
  const unsigned short* Ve = VT + (size_t)eb * 64 * MPAD_;
  int tid = threadIdx.x;
  int w = tid >> 6, l = tid & 63, lr = l & 15, lg = l >> 4;
  int gq = qb * 128 + w * 16 + lr;
  bf16x8 qf[2];
  qf[0] = *reinterpret_cast<const bf16x8*>(Qe + (size_t)gq * 64 + lg * 8);
  qf[1] = *reinterpret_cast<const bf16x8*>(Qe + (size_t)gq * 64 + 32 + lg * 8);
  f32x4 acc[4];
#pragma unroll
  for (int db = 0; db < 4; db++) acc[db] = (f32x4){0.f, 0.f, 0.f, 0.f};
  float mrow = -1e30f, lsum = 0.f;
  char* Pw = Pl_ + w * 2048;
  int srow = tid >> 3, sc = (tid & 7) * 8;
  int ndiag = 2 * qb, ktmax = 2 * qb + 1;
  for (int kt = 0; kt <= ktmax; kt++) {
    int k0 = kt * 64;
    {
      bf16x8 kv = *reinterpret_cast<const bf16x8*>(Ke + (size_t)(k0 + srow) * 64 + sc);
      *reinterpret_cast<bf16x8*>(Ks_ + swz128(srow, sc * 2)) = kv;
      bf16x8 vv = *reinterpret_cast<const bf16x8*>(Ve + (size_t)srow * MPAD_ + k0 + sc);
      *reinterpret_cast<bf16x8*>(Vt_ + swz128(srow, sc * 2)) = vv;
    }
    __syncthreads();
    f32x4 sac[4];
#pragma unroll
    for (int kb = 0; kb < 4; kb++) {
      sac[kb] = (f32x4){0.f, 0.f, 0.f, 0.f};
#pragma unroll
      for (int ds = 0; ds < 2; ds++) {
        bf16x8 kf = *reinterpret_cast<bf16x8*>(Ks_ + swz128(kb * 16 + lr, ds * 64 + lg * 16));
        sac[kb] = mfma16(kf, qf[ds], sac[kb]);
      }
    }
    float p[16];
    float tmax = -1e30f;
    if (kt >= ndiag) {
#pragma unroll
      for (int kb = 0; kb < 4; kb++) {
#pragma unroll
        for (int i = 0; i < 4; i++) {
          int k = k0 + kb * 16 + lg * 4 + i;
          float s = sac[kb][i];
          if (k > gq || k >= MAXLEN_) s = -1e9f;
          p[kb * 4 + i] = s;
          tmax = fmaxf(tmax, s);
        }
      }
    } else {
#pragma unroll
      for (int kb = 0; kb < 4; kb++) {
#pragma unroll
        for (int i = 0; i < 4; i++) {
          float s = sac[kb][i];
          p[kb * 4 + i] = s;
          tmax = fmaxf(tmax, s);
        }
      }
    }
    tmax = fmaxf(tmax, __shfl_xor(tmax, 16));
    tmax = fmaxf(tmax, __shfl_xor(tmax, 32));
    if (!__all(tmax <= mrow + 8.f)) {
      float mnew = fmaxf(mrow, tmax);
      float corr = __expf(mrow - mnew);
      lsum *= corr;
#pragma unroll
      for (int db = 0; db < 4; db++) acc[db] = acc[db] * corr;
      mrow = mnew;
    }
    float psum = 0.f;
#pragma unroll
    for (int j = 0; j < 16; j++) {
      p[j] = __expf(p[j] - mrow);
      psum += p[j];
    }
    psum += __shfl_xor(psum, 16);
    psum += __shfl_xor(psum, 32);
    lsum += psum;
#pragma unroll
    for (int kb = 0; kb < 4; kb++) {
#pragma unroll
      for (int ip = 0; ip < 2; ip++) {
        unsigned u = (unsigned)f2bf(p[kb * 4 + ip * 2]) |
                     ((unsigned)f2bf(p[kb * 4 + ip * 2 + 1]) << 16);
        int k = kb * 16 + lg * 4 + ip * 2;
        *reinterpret_cast<unsigned*>(Pw + swz128(lr, k * 2)) = u;
      }
    }
    bf16x8 pf[2];
#pragma unroll
    for (int ks = 0; ks < 2; ks++)
      pf[ks] = *reinterpret_cast<bf16x8*>(Pw + swz128(lr, ks * 64 + lg * 16));
#pragma unroll
    for (int db = 0; db < 4; db++) {
#pragma unroll
      for (int ks = 0; ks < 2; ks++) {
        bf16x8 vf = *reinterpret_cast<bf16x8*>(Vt_ + swz128(db * 16 + lr, ks * 64 + lg * 16));
        acc[db] = mfma16(vf, pf[ks], acc[db]);
      }
    }
    __syncthreads();
  }
  if (gq < MAXLEN_) {
    float inv = 1.f / lsum;
    unsigned short* op = ctx + ((size_t)eb * MAXLEN_ + gq) * DH_;
#pragma unroll
    for (int db = 0; db < 4; db++) {
      ushort4 pv;
      pv.x = f2bf(acc[db][0] * inv);
      pv.y = f2bf(acc[db][1] * inv);
      pv.z = f2bf(acc[db][2] * inv);
      pv.w = f2bf(acc[db][3] * inv);
      *reinterpret_cast<ushort4*>(op + db * 16 + lg * 4) = pv;
    }
  }
}

// --- Kernel 6: fused FF + expert-sum + residual + LayerNorm (per 32-token tile) ---
// out[b][s0+r][:] = LN( X[b][s0+r][:] + sum_e sel(e,r) (ctx[e,b,m] @ Wff[e] + bff[e]) )
__global__ __launch_bounds__(512) void ffgl_kernel(
    const float* __restrict__ X, const unsigned short* __restrict__ ctx,
    const unsigned short* __restrict__ Wtf, const unsigned short* __restrict__ bffT,
    const int* __restrict__ inv, const float* __restrict__ gamma,
    const float* __restrict__ beta, float* __restrict__ out) {
  __shared__ int invs[E_][32];
  __shared__ __align__(16) char As_[2][32 * 128];  // [32 m][64 k] bf16 swz128
  __shared__ float red1[8][32], red2[8][32];
  __shared__ float mu_s[32], ri_s[32];
  int st = blockIdx.x, b = blockIdx.y;
  int s0 = st * 32;
  int tid = threadIdx.x;
  int w = tid >> 6, l = tid & 63, lr = l & 15, lg = l >> 4;
  {
    int e = tid >> 5, i = tid & 31;
    invs[e][i] = inv[((size_t)(e * B_ + b)) * S_ + s0 + i];
  }
  __syncthreads();
  int si = tid >> 4, sq = tid & 15;  // staging: row si, 8-byte chunk sq
  {
    int m = invs[0][si];
    ushort4 v = {0, 0, 0, 0};
    if (m >= 0)
      v = *reinterpret_cast<const ushort4*>(ctx + ((size_t)(0 * B_ + b) * MAXLEN_ + m) * DH_ + sq * 4);
    *reinterpret_cast<ushort4*>(As_[0] + swz128(si, sq * 8)) = v;
  }
  f32x4 acc[2][8];
#pragma unroll
  for (int a = 0; a < 2; a++)
#pragma unroll
    for (int j = 0; j < 8; j++) acc[a][j] = (f32x4){0.f, 0.f, 0.f, 0.f};
#pragma unroll 1
  for (int e = 0; e < E_; e++) {
    __syncthreads();
    if (e < E_ - 1) {  // prefetch-stage next expert's A tile into other buffer
      int m = invs[e + 1][si];
      ushort4 v = {0, 0, 0, 0};
      if (m >= 0)
        v = *reinterpret_cast<const ushort4*>(ctx + ((size_t)((e + 1) * B_ + b) * MAXLEN_ + m) * DH_ + sq * 4);
      *reinterpret_cast<ushort4*>(As_[(e + 1) & 1] + swz128(si, sq * 8)) = v;
    }
    const char* Ab = As_[e & 1];
    bf16x8 af[2][2];
#pragma unroll
    for (int a = 0; a < 2; a++)
#pragma unroll
      for (int ks = 0; ks < 2; ks++)
        af[a][ks] = *reinterpret_cast<const bf16x8*>(Ab + swz128(a * 16 + lr, ks * 64 + lg * 16));
    const unsigned short* We = Wtf + (size_t)e * D_ * DH_;
#pragma unroll
    for (int j = 0; j < 8; j++) {
      int n = w * 128 + j * 16 + lr;
      bf16x8 b0 = *reinterpret_cast<const bf16x8*>(We + (size_t)n * DH_ + lg * 8);
      bf16x8 b1 = *reinterpret_cast<const bf16x8*>(We + (size_t)n * DH_ + 32 + lg * 8);
      acc[0][j] = mfma16(af[0][0], b0, acc[0][j]);
      acc[1][j] = mfma16(af[1][0], b0, acc[1][j]);
      acc[0][j] = mfma16(af[0][1], b1, acc[0][j]);
      acc[1][j] = mfma16(af[1][1], b1, acc[1][j]);
    }
  }
  // bias pass: A = selection matrix S[32 rows][32 k] (k=e<16), B = bffT
  {
    bf16x8 afb[2];
#pragma unroll
    for (int a = 0; a < 2; a++) {
#pragma unroll
      for (int t = 0; t < 8; t++) {
        int k = lg * 8 + t;
        unsigned short u = 0;
        if (k < E_ && invs[k][a * 16 + lr] >= 0) u = 0x3F80;  // 1.0bf16
        afb[a][t] = (short)u;
      }
    }
#pragma unroll
    for (int j = 0; j < 8; j++) {
      int n = w * 128 + j * 16 + lr;
      bf16x8 bb = *reinterpret_cast<const bf16x8*>(bffT + (size_t)n * 32 + lg * 8);
      acc[0][j] = mfma16(afb[0], bb, acc[0][j]);
      acc[1][j] = mfma16(afb[1], bb, acc[1][j]);
    }
  }
  // epilogue: + X residual, row stats, LayerNorm, store f32
  float p1[2][4], p2[2][4];
#pragma unroll
  for (int a = 0; a < 2; a++)
#pragma unroll
    for (int i = 0; i < 4; i++) { p1[a][i] = 0.f; p2[a][i] = 0.f; }
#pragma unroll
  for (int a = 0; a < 2; a++) {
#pragma unroll
    for (int j = 0; j < 8; j++) {
      int col = w * 128 + j * 16 + lr;
#pragma unroll
      for (int i = 0; i < 4; i++) {
        int row = a * 16 + lg * 4 + i;
        float x = X[((size_t)b * S_ + s0 + row) * D_ + col];
        float v = acc[a][j][i] + x;
        acc[a][j][i] = v;
        p1[a][i] += v;
        p2[a][i] += v * v;
      }
    }
  }
#pragma unroll
  for (int a = 0; a < 2; a++)
#pragma unroll
    for (int i = 0; i < 4; i++) {
#pragma unroll
      for (int off = 1; off < 16; off <<= 1) {
        p1[a][i] += __shfl_xor(p1[a][i], off);
        p2[a][i] += __shfl_xor(p2[a][i], off);
      }
    }
  if (lr == 0) {
#pragma unroll
    for (int a = 0; a < 2; a++)
#pragma unroll
      for (int i = 0; i < 4; i++) {
        int row = a * 16 + lg * 4 + i;
        red1[w][row] = p1[a][i];
        red2[w][row] = p2[a][i];
      }
  }
  __syncthreads();
  if (tid < 32) {
    float s1 = 0.f, s2 = 0.f;
#pragma unroll
    for (int w2 = 0; w2 < 8; w2++) { s1 += red1[w2][tid]; s2 += red2[w2][tid]; }
    float mu = s1 * (1.f / D_);
    float var = s2 * (1.f / D_) - mu * mu;
    mu_s[tid] = mu;
    ri_s[tid] = rsqrtf(var + 1e-5f);
  }
  __syncthreads();
#pragma unroll
  for (int a = 0; a < 2; a++) {
#pragma unroll
    for (int j = 0; j < 8; j++) {
      int col = w * 128 + j * 16 + lr;
      float g = gamma[col];
      float be = beta[col];
#pragma unroll
      for (int i = 0; i < 4; i++) {
        int row = a * 16 + lg * 4 + i;
        out[((size_t)b * S_ + s0 + row) * D_ + col] =
            (acc[a][j][i] - mu_s[row]) * ri_s[row] * g + be;
      }
    }
  }
}

extern "C" void kernel_launch(void* const* d_in, const int* in_sizes, int n_in,
                              void* d_out, int out_size, void* d_ws, size_t ws_size,
                              hipStream_t stream) {
  const float* X = (const float*)d_in[0];
  // d_in[1] = attn_mask (causal, hardcoded)
  const float* w_gate = (const float*)d_in[2];
  const float* b_gate = (const float*)d_in[3];
  const float* W_qkv = (const float*)d_in[4];
  const float* W_ff = (const float*)d_in[5];
  const float* b_ff = (const float*)d_in[6];
  const float* ln_g = (const float*)d_in[7];
  const float* ln_b = (const float*)d_in[8];
  float* out = (float*)d_out;

  char* ws = (char*)d_ws;
  float* masked_t = (float*)(ws);                           //   524288 B
  int* seq_ids = (int*)(ws + 1048576);                      //   314368 B
  unsigned short* Qr = (unsigned short*)(ws + 1362944);     // 10485760 B
  unsigned short* Kr = (unsigned short*)(ws + 11848704);    // 10485760 B
  unsigned short* VT = (unsigned short*)(ws + 22334464);    // 10485760 B
  unsigned short* ctx = (unsigned short*)(ws + 32820224);   // 10059776 B
  unsigned short* Xb16 = (unsigned short*)(ws + 42880000);  // 16777216 B
  unsigned short* Wtq = (unsigned short*)(ws + 59657216);   //  6291456 B
  unsigned short* Wtf = (unsigned short*)(ws + 65948672);   //  2097152 B
  float* wgT = (float*)(ws + 68045824);                     //    65536 B
  unsigned short* bffT = (unsigned short*)(ws + 68111360);  //    65536 B
  int* inv = (int*)(ws + 68176896);                         //   524288 B
  // total 68701184 B

  cvt_wqkv_kernel<<<dim3(32, 16), 256, 0, stream>>>(W_qkv, Wtq);
  cvt_wff_kernel<<<dim3(16, 16), 256, 0, stream>>>(W_ff, Wtf);
  cvt_wgt_kernel<<<64, 256, 0, stream>>>(w_gate, wgT);
  cvt_bff_kernel<<<4, 256, 0, stream>>>(b_ff, bffT);
  gate_kernel<<<2048, 256, 0, stream>>>(X, wgT, b_gate, masked_t, Xb16);
  select_kernel<<<E_ * B_, 256, 0, stream>>>(masked_t, seq_ids);
  inv_kernel<<<E_ * B_, 256, 0, stream>>>(seq_ids, inv);
  qkv_kernel<<<dim3(10, 64), 512, 0, stream>>>(Xb16, Wtq, seq_ids, Qr, Kr, VT);
  attn_kernel<<<dim3(10, 64), 512, 0, stream>>>(Qr, Kr, VT, ctx);
  ffgl_kernel<<<dim3(S_ / 32, B_), 512, 0, stream>>>(X, ctx, Wtf, bffT, inv,
                                                     ln_g, ln_b, out);
}

// Round 9
// 258.556 us; speedup vs baseline: 1.4577x; 1.0110x over previous
//
#include <hip/hip_runtime.h>
#include <math.h>

#define B_ 4
#define S_ 2048
#define D_ 1024
#define E_ 16
#define DH_ 64
#define TOPK_ 8
#define MAXLEN_ 1228
#define MPAD_ 1280
#define CAPF 4.0f
#define EPS_ 1e-6f

typedef __attribute__((ext_vector_type(8))) short bf16x8;
typedef __attribute__((ext_vector_type(4))) float f32x4;

__device__ inline f32x4 mfma16(bf16x8 a, bf16x8 b, f32x4 c) {
  return __builtin_amdgcn_mfma_f32_16x16x32_bf16(a, b, c, 0, 0, 0);
}
__device__ inline float bf2f(unsigned short u) {
  return __uint_as_float(((unsigned)u) << 16);
}
__device__ inline unsigned short f2bf(float f) {
  unsigned u = __float_as_uint(f);
  unsigned r = (u + 0x7FFFu + ((u >> 16) & 1u)) >> 16;
  return (unsigned short)r;
}
__device__ inline ushort4 pk4(float4 v) {
  ushort4 r;
  r.x = f2bf(v.x); r.y = f2bf(v.y); r.z = f2bf(v.z); r.w = f2bf(v.w);
  return r;
}
// XOR-swizzled LDS addressing (byte offsets), 128B rows.
__device__ inline int swz128(int row, int off) { return row * 128 + (off ^ ((row & 7) << 4)); }

// ---------------- one-time converts ----------------
// W_qkv[e][1024 k][192 n] f32 -> Wt[e][192 n][1024 k] bf16
__global__ __launch_bounds__(256) void cvt_wqkv_kernel(
    const float* __restrict__ W, unsigned short* __restrict__ Wt) {
  __shared__ short T[192][40];
  int e = blockIdx.y, k0 = blockIdx.x * 32;
  const float* Wp = W + (size_t)e * D_ * 192 + (size_t)k0 * 192;
  int tid = threadIdx.x;
#pragma unroll
  for (int it = 0; it < 24; it++) {
    int idx = tid + it * 256;  // 0..6143
    int kr = idx / 192, n = idx % 192;
    T[n][kr] = (short)f2bf(Wp[(size_t)kr * 192 + n]);
  }
  __syncthreads();
  unsigned short* Wo = Wt + (size_t)e * 192 * 1024 + k0;
#pragma unroll
  for (int it = 0; it < 3; it++) {
    int idx = tid + it * 256;  // 0..767
    int n = idx >> 2, c = idx & 3;
    bf16x8 v = *reinterpret_cast<bf16x8*>(&T[n][c * 8]);
    *reinterpret_cast<bf16x8*>(Wo + (size_t)n * 1024 + c * 8) = v;
  }
}

// W_ff[e][64 k][1024 n] f32 -> Wt[e][1024 n][64 k] bf16
__global__ __launch_bounds__(256) void cvt_wff_kernel(
    const float* __restrict__ W, unsigned short* __restrict__ Wt) {
  __shared__ short T[64][72];
  int e = blockIdx.y, n0 = blockIdx.x * 64;
  const float* Wp = W + (size_t)e * DH_ * D_;
  int tid = threadIdx.x;
#pragma unroll
  for (int it = 0; it < 16; it++) {
    int idx = tid + it * 256;  // 0..4095
    int k = idx >> 6, n = idx & 63;
    T[n][k] = (short)f2bf(Wp[(size_t)k * D_ + n0 + n]);
  }
  __syncthreads();
  unsigned short* Wo = Wt + (size_t)e * D_ * DH_ + (size_t)n0 * DH_;
#pragma unroll
  for (int it = 0; it < 2; it++) {
    int idx = tid + it * 256;  // 0..511
    int n = idx >> 3, c = idx & 7;
    bf16x8 v = *reinterpret_cast<bf16x8*>(&T[n][c * 8]);
    *reinterpret_cast<bf16x8*>(Wo + (size_t)n * DH_ + c * 8) = v;
  }
}

// wg[1024 d][16 e] f32 -> wgT[16 e][1024 d] f32 (64 KB, one-time)
__global__ __launch_bounds__(256) void cvt_wgt_kernel(
    const float* __restrict__ wg, float* __restrict__ wgT) {
  int idx = blockIdx.x * 256 + threadIdx.x;  // 0..16383
  int e = idx >> 10, d = idx & 1023;
  wgT[idx] = wg[(size_t)d * E_ + e];
}

// bff[16 e][1024 n] f32 -> bffT[1024 n][32 k] bf16 (k=e for e<16, else 0)
__global__ __launch_bounds__(256) void cvt_bff_kernel(
    const float* __restrict__ bff, unsigned short* __restrict__ bffT) {
  int n = blockIdx.x * 256 + threadIdx.x;  // 0..1023
  unsigned short* o = bffT + (size_t)n * 32;
#pragma unroll
  for (int e = 0; e < E_; e++) o[e] = f2bf(bff[(size_t)e * D_ + n]);
#pragma unroll
  for (int e = E_; e < 32; e++) o[e] = 0;
}

// --------- Kernel 1: gating -> masked_t[e][b][s]; also emits Xb16 ---------
__global__ __launch_bounds__(256) void gate_kernel(
    const float* __restrict__ X, const float* __restrict__ wgT,
    const float* __restrict__ bg, float* __restrict__ masked_t,
    unsigned short* __restrict__ Xb) {
  int token = blockIdx.x * 4 + (threadIdx.x >> 6);  // b*S + s
  int lane = threadIdx.x & 63;
  int b = token / S_, s = token % S_;
  const float* xrow = X + (size_t)token * D_;
  unsigned short* xbrow = Xb + (size_t)token * D_;
  float acc[E_];
#pragma unroll
  for (int e = 0; e < E_; e++) acc[e] = 0.f;
#pragma unroll
  for (int d0 = 0; d0 < D_; d0 += 256) {
    int d = d0 + lane * 4;
    float4 xv = *reinterpret_cast<const float4*>(xrow + d);
    *reinterpret_cast<ushort4*>(xbrow + d) = pk4(xv);  // fused bf16 convert
#pragma unroll
    for (int e = 0; e < E_; e++) {
      float4 wv = *reinterpret_cast<const float4*>(wgT + (size_t)e * D_ + d);
      acc[e] += xv.x * wv.x + xv.y * wv.y + xv.z * wv.z + xv.w * wv.w;
    }
  }
#pragma unroll
  for (int e = 0; e < E_; e++) {
    float v = acc[e];
    for (int off = 32; off; off >>= 1) v += __shfl_xor(v, off);
    acc[e] = v;
  }
  if (lane == 0) {
    float lg[E_], sc[E_], mx = -1e30f;
#pragma unroll
    for (int e = 0; e < E_; e++) {
      lg[e] = acc[e] + bg[e];
      mx = fmaxf(mx, lg[e]);
    }
    float den = 0.f;
#pragma unroll
    for (int e = 0; e < E_; e++) {
      sc[e] = expf(lg[e] - mx);
      den += sc[e];
    }
#pragma unroll
    for (int e = 0; e < E_; e++) sc[e] /= den;
#pragma unroll
    for (int e = 0; e < E_; e++) {
      int rank = 0;
      for (int j = 0; j < E_; j++)
        if (lg[j] > lg[e] || (lg[j] == lg[e] && j < e)) rank++;
      float m = (rank < TOPK_) ? sc[e] : 0.f;
      masked_t[((size_t)e * B_ + b) * S_ + s] = m;
    }
  }
}

// ------- Kernel 3: radix-select top-MAXLEN per (e,b), route fused --------
__global__ __launch_bounds__(256) void select_kernel(
    const float* __restrict__ masked_t, int* __restrict__ seq_ids) {
  __shared__ unsigned vals[S_];
  __shared__ int hist[256];
  __shared__ int wsum[4];
  __shared__ int tsum[4];
  __shared__ unsigned sh_prefix;
  __shared__ int sh_rank;
  int eb = blockIdx.x;
  int e = eb >> 2, b = eb & 3;
  int tid = threadIdx.x;
  int lane = tid & 63, wv = tid >> 6;
  const float* mb0 = masked_t + (size_t)e * B_ * S_;
  for (int i = tid; i < S_; i += 256) {
    float v0 = mb0[i];
    float v1 = mb0[S_ + i];
    float v2 = mb0[2 * S_ + i];
    float v3 = mb0[3 * S_ + i];
    float d = EPS_;
    d += v0; d += v1; d += v2; d += v3;  // same order as route_kernel
    float mv = mb0[(size_t)b * S_ + i];
    vals[i] = __float_as_uint(mv / d * CAPF);
  }
  if (tid == 0) { sh_prefix = 0u; sh_rank = MAXLEN_; }
  __syncthreads();
  for (int shift = 24; shift >= 0; shift -= 8) {
    hist[tid] = 0;
    __syncthreads();
    unsigned pfx = sh_prefix;
    unsigned maskhi = (shift == 24) ? 0u : (0xFFFFFFFFu << (shift + 8));
    for (int i = tid; i < S_; i += 256) {
      unsigned v = vals[i];
      if ((v & maskhi) == pfx) atomicAdd(&hist[(v >> shift) & 255], 1);
    }
    __syncthreads();
    int bin = 255 - tid;
    int h = hist[bin];
    int sc = h;
    for (int off = 1; off < 64; off <<= 1) {
      int n = __shfl_up(sc, off);
      if (lane >= off) sc += n;
    }
    if (lane == 63) wsum[wv] = sc;
    __syncthreads();
    int add = 0;
#pragma unroll
    for (int k = 0; k < 4; k++)
      if (k < wv) add += wsum[k];
    sc += add;
    int rank = sh_rank;
    __syncthreads();
    if (sc - h < rank && rank <= sc) {
      sh_prefix = pfx | ((unsigned)bin << shift);
      sh_rank = rank - (sc - h);
    }
    __syncthreads();
  }
  unsigned T = sh_prefix;
  int r = sh_rank;
  int i0 = tid * 8;
  int eqf[8], gtf[8];
  int eqtot = 0;
#pragma unroll
  for (int k = 0; k < 8; k++) {
    unsigned v = vals[i0 + k];
    eqf[k] = (v == T) ? 1 : 0;
    gtf[k] = (v > T) ? 1 : 0;
    eqtot += eqf[k];
  }
  int esc = eqtot;
  for (int off = 1; off < 64; off <<= 1) {
    int n = __shfl_up(esc, off);
    if (lane >= off) esc += n;
  }
  if (lane == 63) tsum[wv] = esc;
  __syncthreads();
  int eadd = 0;
#pragma unroll
  for (int k = 0; k < 4; k++)
    if (k < wv) eadd += tsum[k];
  int erun = esc - eqtot + eadd;
  int self_[8];
  int stot = 0;
#pragma unroll
  for (int k = 0; k < 8; k++) {
    int s = gtf[k] | (eqf[k] & (erun < r ? 1 : 0));
    erun += eqf[k];
    self_[k] = s;
    stot += s;
  }
  __syncthreads();
  int ssc = stot;
  for (int off = 1; off < 64; off <<= 1) {
    int n = __shfl_up(ssc, off);
    if (lane >= off) ssc += n;
  }
  if (lane == 63) tsum[wv] = ssc;
  __syncthreads();
  int sadd = 0;
#pragma unroll
  for (int k = 0; k < 4; k++)
    if (k < wv) sadd += tsum[k];
  int pos = ssc - stot + sadd;
  int* outp = seq_ids + (size_t)eb * MAXLEN_;
#pragma unroll
  for (int k = 0; k < 8; k++) {
    if (self_[k]) outp[pos++] = i0 + k;
  }
}

// --------- Kernel 3b: inverse map inv[eb][s] = m (or -1) ---------
__global__ __launch_bounds__(256) void inv_kernel(
    const int* __restrict__ seq_ids, int* __restrict__ inv) {
  int eb = blockIdx.x;
  int tid = threadIdx.x;
  int* ip = inv + (size_t)eb * S_;
  for (int i = tid; i < S_; i += 256) ip[i] = -1;
  __syncthreads();
  const int* sid = seq_ids + (size_t)eb * MAXLEN_;
  for (int m = tid; m < MAXLEN_; m += 256) ip[sid[m]] = m;
}

// ---------------- Kernel 4: gathered QKV GEMM (bf16 MFMA) ----------------
__global__ __launch_bounds__(512) void qkv_kernel(
    const unsigned short* __restrict__ Xb, const unsigned short* __restrict__ Wt,
    const int* __restrict__ seq_ids, unsigned short* __restrict__ Qr,
    unsigned short* __restrict__ Kr, unsigned short* __restrict__ VT) {
  __shared__ __align__(16) char Bt_[2][192 * 128];  // [192 n][64 k] bf16 swz128
  __shared__ int rows[128];
  int eb = blockIdx.y;
  int e = eb >> 2, b = eb & 3;
  int m0 = blockIdx.x * 128;
  int tid = threadIdx.x;
  int w = tid >> 6, l = tid & 63, lr = l & 15, lg = l >> 4;
  int wm = w & 3, wn = w >> 2;
  const int* sid = seq_ids + (size_t)eb * MAXLEN_;
  if (tid < 128) {
    int m = m0 + tid;
    rows[tid] = (m < MAXLEN_) ? sid[m] : 0;
  }
  __syncthreads();
  const unsigned short* Wm = Wt + (size_t)e * 192 * 1024;
  const unsigned short* Xbb = Xb + (size_t)b * S_ * D_;
  const unsigned short* ap0 = Xbb + (size_t)rows[wm * 32 + lr] * D_;
  const unsigned short* ap1 = Xbb + (size_t)rows[wm * 32 + 16 + lr] * D_;
  int s0 = tid, s1 = tid + 512, s2 = tid + 1024;
  f32x4 acc[2][6];
#pragma unroll
  for (int a = 0; a < 2; a++)
#pragma unroll
    for (int j = 0; j < 6; j++) acc[a][j] = (f32x4){0.f, 0.f, 0.f, 0.f};
  bf16x8 stg0 = *reinterpret_cast<const bf16x8*>(Wm + (size_t)(s0 >> 3) * 1024 + (s0 & 7) * 8);
  bf16x8 stg1 = *reinterpret_cast<const bf16x8*>(Wm + (size_t)(s1 >> 3) * 1024 + (s1 & 7) * 8);
  bf16x8 stg2 = *reinterpret_cast<const bf16x8*>(Wm + (size_t)(s2 >> 3) * 1024 + (s2 & 7) * 8);
  bf16x8 a00 = *reinterpret_cast<const bf16x8*>(ap0 + lg * 8);
  bf16x8 a01 = *reinterpret_cast<const bf16x8*>(ap0 + 32 + lg * 8);
  bf16x8 a10 = *reinterpret_cast<const bf16x8*>(ap1 + lg * 8);
  bf16x8 a11 = *reinterpret_cast<const bf16x8*>(ap1 + 32 + lg * 8);
  for (int t = 0; t < 16; t++) {
    char* buf = Bt_[t & 1];
    *reinterpret_cast<bf16x8*>(buf + swz128(s0 >> 3, (s0 & 7) * 16)) = stg0;
    *reinterpret_cast<bf16x8*>(buf + swz128(s1 >> 3, (s1 & 7) * 16)) = stg1;
    *reinterpret_cast<bf16x8*>(buf + swz128(s2 >> 3, (s2 & 7) * 16)) = stg2;
    bf16x8 n0, n1, n2, b00, b01, b10, b11;
    if (t < 15) {
      int kn = (t + 1) * 64;
      n0 = *reinterpret_cast<const bf16x8*>(Wm + (size_t)(s0 >> 3) * 1024 + kn + (s0 & 7) * 8);
      n1 = *reinterpret_cast<const bf16x8*>(Wm + (size_t)(s1 >> 3) * 1024 + kn + (s1 & 7) * 8);
      n2 = *reinterpret_cast<const bf16x8*>(Wm + (size_t)(s2 >> 3) * 1024 + kn + (s2 & 7) * 8);
      b00 = *reinterpret_cast<const bf16x8*>(ap0 + kn + lg * 8);
      b01 = *reinterpret_cast<const bf16x8*>(ap0 + kn + 32 + lg * 8);
      b10 = *reinterpret_cast<const bf16x8*>(ap1 + kn + lg * 8);
      b11 = *reinterpret_cast<const bf16x8*>(ap1 + kn + 32 + lg * 8);
    }
    __syncthreads();
#pragma unroll
    for (int j = 0; j < 6; j++) {
      int nr = (wn * 6 + j) * 16 + lr;
      bf16x8 bf0 = *reinterpret_cast<bf16x8*>(buf + swz128(nr, lg * 16));
      bf16x8 bf1 = *reinterpret_cast<bf16x8*>(buf + swz128(nr, 64 + lg * 16));
      acc[0][j] = mfma16(a00, bf0, acc[0][j]);
      acc[1][j] = mfma16(a10, bf0, acc[1][j]);
      acc[0][j] = mfma16(a01, bf1, acc[0][j]);
      acc[1][j] = mfma16(a11, bf1, acc[1][j]);
    }
    if (t < 15) {
      stg0 = n0; stg1 = n1; stg2 = n2;
      a00 = b00; a01 = b01; a10 = b10; a11 = b11;
    }
  }
  unsigned short* Qe = Qr + (size_t)eb * MPAD_ * 64;
  unsigned short* Ke = Kr + (size_t)eb * MPAD_ * 64;
  unsigned short* Ve = VT + (size_t)eb * 64 * MPAD_;
#pragma unroll
  for (int a = 0; a < 2; a++) {
    int mb = m0 + wm * 32 + a * 16 + lg * 4;
#pragma unroll
    for (int j = 0; j < 6; j++) {
      int nbg = wn * 6 + j;
      if (nbg < 4) {
#pragma unroll
        for (int i = 0; i < 4; i++) {
          int m = mb + i;
          float v = (m < MAXLEN_) ? acc[a][j][i] * 0.125f : 0.f;
          Qe[(size_t)m * 64 + nbg * 16 + lr] = f2bf(v);
        }
      } else if (nbg < 8) {
#pragma unroll
        for (int i = 0; i < 4; i++) {
          int m = mb + i;
          float v = (m < MAXLEN_) ? acc[a][j][i] : 0.f;
          Ke[(size_t)m * 64 + (nbg - 4) * 16 + lr] = f2bf(v);
        }
      } else {
        ushort4 pv;
        pv.x = (mb + 0 < MAXLEN_) ? f2bf(acc[a][j][0]) : (unsigned short)0;
        pv.y = (mb + 1 < MAXLEN_) ? f2bf(acc[a][j][1]) : (unsigned short)0;
        pv.z = (mb + 2 < MAXLEN_) ? f2bf(acc[a][j][2]) : (unsigned short)0;
        pv.w = (mb + 3 < MAXLEN_) ? f2bf(acc[a][j][3]) : (unsigned short)0;
        *reinterpret_cast<ushort4*>(Ve + (size_t)((nbg - 8) * 16 + lr) * MPAD_ + mb) = pv;
      }
    }
  }
}

// ------------- Kernel 5: flash attention, bf16 MFMA, per (e,b) -------------
__global__ __launch_bounds__(512) void attn_kernel(
    const unsigned short* __restrict__ Qr, const unsigned short* __restrict__ Kr,
    const unsigned short* __restrict__ VT, unsigned short* __restrict__ ctx) {
  __shared__ __align__(16) char Ks_[64 * 128];      // [64 k][64 d] swz128
  __shared__ __align__(16) char Vt_[64 * 128];      // [64 dv][64 k] swz128
  __shared__ __align__(16) char Pl_[8 * 16 * 128];  // per-wave [16 q][64 k]
  int qb = 9 - blockIdx.x;  // longest first
  int eb = blockIdx.y;
  const unsigned short* Qe = Qr + (size_t)eb * MPAD_ * 64;
  const unsigned short* Ke = Kr + (size_t)eb * MPAD_ * 64;
  const unsigned short* Ve = VT + (size_t)eb * 64 * MPAD_;
  int tid = threadIdx.x;
  int w = tid >> 6, l = tid & 63, lr = l & 15, lg = l >> 4;
  int gq = qb * 128 + w * 16 + lr;
  bf16x8 qf[2];
  qf[0] = *reinterpret_cast<const bf16x8*>(Qe + (size_t)gq * 64 + lg * 8);
  qf[1] = *reinterpret_cast<const bf16x8*>(Qe + (size_t)gq * 64 + 32 + lg * 8);
  f32x4 acc[4];
#pragma unroll
  for (int db = 0; db < 4; db++) acc[db] = (f32x4){0.f, 0.f, 0.f, 0.f};
  float mrow = -1e30f, lsum = 0.f;
  char* Pw = Pl_ + w * 2048;
  int srow = tid >> 3, sc = (tid & 7) * 8;
  int ndiag = 2 * qb, ktmax = 2 * qb + 1;
  for (int kt = 0; kt <= ktmax; kt++) {
    int k0 = kt * 64;
    {
      bf16x8 kv = *reinterpret_cast<const bf16x8*>(Ke + (size_t)(k0 + srow) * 64 + sc);
      *reinterpret_cast<bf16x8*>(Ks_ + swz128(srow, sc * 2)) = kv;
      bf16x8 vv = *reinterpret_cast<const bf16x8*>(Ve + (size_t)srow * MPAD_ + k0 + sc);
      *reinterpret_cast<bf16x8*>(Vt_ + swz128(srow, sc * 2)) = vv;
    }
    __syncthreads();
    f32x4 sac[4];
#pragma unroll
    for (int kb = 0; kb < 4; kb++) {
      sac[kb] = (f32x4){0.f, 0.f, 0.f, 0.f};
#pragma unroll
      for (int ds = 0; ds < 2; ds++) {
        bf16x8 kf = *reinterpret_cast<bf16x8*>(Ks_ + swz128(kb * 16 + lr, ds * 64 + lg * 16));
        sac[kb] = mfma16(kf, qf[ds], sac[kb]);
      }
    }
    float p[16];
    float tmax = -1e30f;
    if (kt >= ndiag) {
#pragma unroll
      for (int kb = 0; kb < 4; kb++) {
#pragma unroll
        for (int i = 0; i < 4; i++) {
          int k = k0 + kb * 16 + lg * 4 + i;
          float s = sac[kb][i];
          if (k > gq || k >= MAXLEN_) s = -1e9f;
          p[kb * 4 + i] = s;
          tmax = fmaxf(tmax, s);
        }
      }
    } else {
#pragma unroll
      for (int kb = 0; kb < 4; kb++) {
#pragma unroll
        for (int i = 0; i < 4; i++) {
          float s = sac[kb][i];
          p[kb * 4 + i] = s;
          tmax = fmaxf(tmax, s);
        }
      }
    }
    tmax = fmaxf(tmax, __shfl_xor(tmax, 16));
    tmax = fmaxf(tmax, __shfl_xor(tmax, 32));
    if (!__all(tmax <= mrow + 8.f)) {
      float mnew = fmaxf(mrow, tmax);
      float corr = __expf(mrow - mnew);
      lsum *= corr;
#pragma unroll
      for (int db = 0; db < 4; db++) acc[db] = acc[db] * corr;
      mrow = mnew;
    }
    float psum = 0.f;
#pragma unroll
    for (int j = 0; j < 16; j++) {
      p[j] = __expf(p[j] - mrow);
      psum += p[j];
    }
    psum += __shfl_xor(psum, 16);
    psum += __shfl_xor(psum, 32);
    lsum += psum;
#pragma unroll
    for (int kb = 0; kb < 4; kb++) {
#pragma unroll
      for (int ip = 0; ip < 2; ip++) {
        unsigned u = (unsigned)f2bf(p[kb * 4 + ip * 2]) |
                     ((unsigned)f2bf(p[kb * 4 + ip * 2 + 1]) << 16);
        int k = kb * 16 + lg * 4 + ip * 2;
        *reinterpret_cast<unsigned*>(Pw + swz128(lr, k * 2)) = u;
      }
    }
    bf16x8 pf[2];
#pragma unroll
    for (int ks = 0; ks < 2; ks++)
      pf[ks] = *reinterpret_cast<bf16x8*>(Pw + swz128(lr, ks * 64 + lg * 16));
#pragma unroll
    for (int db = 0; db < 4; db++) {
#pragma unroll
      for (int ks = 0; ks < 2; ks++) {
        bf16x8 vf = *reinterpret_cast<bf16x8*>(Vt_ + swz128(db * 16 + lr, ks * 64 + lg * 16));
        acc[db] = mfma16(vf, pf[ks], acc[db]);
      }
    }
    __syncthreads();
  }
  if (gq < MAXLEN_) {
    float inv = 1.f / lsum;
    unsigned short* op = ctx + ((size_t)eb * MAXLEN_ + gq) * DH_;
#pragma unroll
    for (int db = 0; db < 4; db++) {
      ushort4 pv;
      pv.x = f2bf(acc[db][0] * inv);
      pv.y = f2bf(acc[db][1] * inv);
      pv.z = f2bf(acc[db][2] * inv);
      pv.w = f2bf(acc[db][3] * inv);
      *reinterpret_cast<ushort4*>(op + db * 16 + lg * 4) = pv;
    }
  }
}

// --- Kernel 6: fused FF + expert-sum + residual + LayerNorm ---
// 1024 threads / 16 waves; wave w owns cols [w*64, w*64+64).
__global__ __launch_bounds__(1024) void ffgl_kernel(
    const float* __restrict__ X, const unsigned short* __restrict__ ctx,
    const unsigned short* __restrict__ Wtf, const unsigned short* __restrict__ bffT,
    const int* __restrict__ inv, const float* __restrict__ gamma,
    const float* __restrict__ beta, float* __restrict__ out) {
  __shared__ int invs[E_][32];
  __shared__ __align__(16) char As_[2][32 * 128];  // [32 m][64 k] bf16 swz128
  __shared__ float red1[16][32], red2[16][32];
  __shared__ float mu_s[32], ri_s[32];
  int st = blockIdx.x, b = blockIdx.y;
  int s0 = st * 32;
  int tid = threadIdx.x;
  int w = tid >> 6, l = tid & 63, lr = l & 15, lg = l >> 4;
  if (tid < 512) {
    int e = tid >> 5, i = tid & 31;
    invs[e][i] = inv[((size_t)(e * B_ + b)) * S_ + s0 + i];
  }
  __syncthreads();
  int si = tid >> 5, sq = tid & 31;  // staging: row si, 4-byte chunk sq
  {
    int m = invs[0][si];
    ushort2 v = {0, 0};
    if (m >= 0)
      v = *reinterpret_cast<const ushort2*>(ctx + ((size_t)(0 * B_ + b) * MAXLEN_ + m) * DH_ + sq * 2);
    *reinterpret_cast<ushort2*>(As_[0] + swz128(si, sq * 4)) = v;
  }
  f32x4 acc[2][4];
#pragma unroll
  for (int a = 0; a < 2; a++)
#pragma unroll
    for (int j = 0; j < 4; j++) acc[a][j] = (f32x4){0.f, 0.f, 0.f, 0.f};
#pragma unroll 1
  for (int e = 0; e < E_; e++) {
    __syncthreads();
    if (e < E_ - 1) {  // prefetch-stage next expert's A tile into other buffer
      int m = invs[e + 1][si];
      ushort2 v = {0, 0};
      if (m >= 0)
        v = *reinterpret_cast<const ushort2*>(ctx + ((size_t)((e + 1) * B_ + b) * MAXLEN_ + m) * DH_ + sq * 2);
      *reinterpret_cast<ushort2*>(As_[(e + 1) & 1] + swz128(si, sq * 4)) = v;
    }
    const char* Ab = As_[e & 1];
    bf16x8 af[2][2];
#pragma unroll
    for (int a = 0; a < 2; a++)
#pragma unroll
      for (int ks = 0; ks < 2; ks++)
        af[a][ks] = *reinterpret_cast<const bf16x8*>(Ab + swz128(a * 16 + lr, ks * 64 + lg * 16));
    const unsigned short* We = Wtf + (size_t)e * D_ * DH_;
#pragma unroll
    for (int j = 0; j < 4; j++) {
      int n = w * 64 + j * 16 + lr;
      bf16x8 b0 = *reinterpret_cast<const bf16x8*>(We + (size_t)n * DH_ + lg * 8);
      bf16x8 b1 = *reinterpret_cast<const bf16x8*>(We + (size_t)n * DH_ + 32 + lg * 8);
      acc[0][j] = mfma16(af[0][0], b0, acc[0][j]);
      acc[1][j] = mfma16(af[1][0], b0, acc[1][j]);
      acc[0][j] = mfma16(af[0][1], b1, acc[0][j]);
      acc[1][j] = mfma16(af[1][1], b1, acc[1][j]);
    }
  }
  // bias pass: A = selection matrix S[32 rows][32 k] (k=e<16), B = bffT
  {
    bf16x8 afb[2];
#pragma unroll
    for (int a = 0; a < 2; a++) {
#pragma unroll
      for (int t = 0; t < 8; t++) {
        int k = lg * 8 + t;
        unsigned short u = 0;
        if (k < E_ && invs[k][a * 16 + lr] >= 0) u = 0x3F80;  // 1.0bf16
        afb[a][t] = (short)u;
      }
    }
#pragma unroll
    for (int j = 0; j < 4; j++) {
      int n = w * 64 + j * 16 + lr;
      bf16x8 bb = *reinterpret_cast<const bf16x8*>(bffT + (size_t)n * 32 + lg * 8);
      acc[0][j] = mfma16(afb[0], bb, acc[0][j]);
      acc[1][j] = mfma16(afb[1], bb, acc[1][j]);
    }
  }
  // epilogue: + X residual, row stats, LayerNorm, store f32
  float p1[2][4], p2[2][4];
#pragma unroll
  for (int a = 0; a < 2; a++)
#pragma unroll
    for (int i = 0; i < 4; i++) { p1[a][i] = 0.f; p2[a][i] = 0.f; }
#pragma unroll
  for (int a = 0; a < 2; a++) {
#pragma unroll
    for (int j = 0; j < 4; j++) {
      int col = w * 64 + j * 16 + lr;
#pragma unroll
      for (int i = 0; i < 4; i++) {
        int row = a * 16 + lg * 4 + i;
        float x = X[((size_t)b * S_ + s0 + row) * D_ + col];
        float v = acc[a][j][i] + x;
        acc[a][j][i] = v;
        p1[a][i] += v;
        p2[a][i] += v * v;
      }
    }
  }
#pragma unroll
  for (int a = 0; a < 2; a++)
#pragma unroll
    for (int i = 0; i < 4; i++) {
#pragma unroll
      for (int off = 1; off < 16; off <<= 1) {
        p1[a][i] += __shfl_xor(p1[a][i], off);
        p2[a][i] += __shfl_xor(p2[a][i], off);
      }
    }
  if (lr == 0) {
#pragma unroll
    for (int a = 0; a < 2; a++)
#pragma unroll
      for (int i = 0; i < 4; i++) {
        int row = a * 16 + lg * 4 + i;
        red1[w][row] = p1[a][i];
        red2[w][row] = p2[a][i];
      }
  }
  __syncthreads();
  if (tid < 32) {
    float s1 = 0.f, s2 = 0.f;
#pragma unroll
    for (int w2 = 0; w2 < 16; w2++) { s1 += red1[w2][tid]; s2 += red2[w2][tid]; }
    float mu = s1 * (1.f / D_);
    float var = s2 * (1.f / D_) - mu * mu;
    mu_s[tid] = mu;
    ri_s[tid] = rsqrtf(var + 1e-5f);
  }
  __syncthreads();
#pragma unroll
  for (int a = 0; a < 2; a++) {
#pragma unroll
    for (int j = 0; j < 4; j++) {
      int col = w * 64 + j * 16 + lr;
      float g = gamma[col];
      float be = beta[col];
#pragma unroll
      for (int i = 0; i < 4; i++) {
        int row = a * 16 + lg * 4 + i;
        out[((size_t)b * S_ + s0 + row) * D_ + col] =
            (acc[a][j][i] - mu_s[row]) * ri_s[row] * g + be;
      }
    }
  }
}

extern "C" void kernel_launch(void* const* d_in, const int* in_sizes, int n_in,
                              void* d_out, int out_size, void* d_ws, size_t ws_size,
                              hipStream_t stream) {
  const float* X = (const float*)d_in[0];
  // d_in[1] = attn_mask (causal, hardcoded)
  const float* w_gate = (const float*)d_in[2];
  const float* b_gate = (const float*)d_in[3];
  const float* W_qkv = (const float*)d_in[4];
  const float* W_ff = (const float*)d_in[5];
  const float* b_ff = (const float*)d_in[6];
  const float* ln_g = (const float*)d_in[7];
  const float* ln_b = (const float*)d_in[8];
  float* out = (float*)d_out;

  char* ws = (char*)d_ws;
  float* masked_t = (float*)(ws);                           //   524288 B
  int* seq_ids = (int*)(ws + 1048576);                      //   314368 B
  unsigned short* Qr = (unsigned short*)(ws + 1362944);     // 10485760 B
  unsigned short* Kr = (unsigned short*)(ws + 11848704);    // 10485760 B
  unsigned short* VT = (unsigned short*)(ws + 22334464);    // 10485760 B
  unsigned short* ctx = (unsigned short*)(ws + 32820224);   // 10059776 B
  unsigned short* Xb16 = (unsigned short*)(ws + 42880000);  // 16777216 B
  unsigned short* Wtq = (unsigned short*)(ws + 59657216);   //  6291456 B
  unsigned short* Wtf = (unsigned short*)(ws + 65948672);   //  2097152 B
  float* wgT = (float*)(ws + 68045824);                     //    65536 B
  unsigned short* bffT = (unsigned short*)(ws + 68111360);  //    65536 B
  int* inv = (int*)(ws + 68176896);                         //   524288 B
  // total 68701184 B

  cvt_wqkv_kernel<<<dim3(32, 16), 256, 0, stream>>>(W_qkv, Wtq);
  cvt_wff_kernel<<<dim3(16, 16), 256, 0, stream>>>(W_ff, Wtf);
  cvt_wgt_kernel<<<64, 256, 0, stream>>>(w_gate, wgT);
  cvt_bff_kernel<<<4, 256, 0, stream>>>(b_ff, bffT);
  gate_kernel<<<2048, 256, 0, stream>>>(X, wgT, b_gate, masked_t, Xb16);
  select_kernel<<<E_ * B_, 256, 0, stream>>>(masked_t, seq_ids);
  inv_kernel<<<E_ * B_, 256, 0, stream>>>(seq_ids, inv);
  qkv_kernel<<<dim3(10, 64), 512, 0, stream>>>(Xb16, Wtq, seq_ids, Qr, Kr, VT);
  attn_kernel<<<dim3(10, 64), 512, 0, stream>>>(Qr, Kr, VT, ctx);
  ffgl_kernel<<<dim3(S_ / 32, B_), 1024, 0, stream>>>(X, ctx, Wtf, bffT, inv,
                                                      ln_g, ln_b, out);
}

// Round 10
// 239.710 us; speedup vs baseline: 1.5724x; 1.0786x over previous
//
#include <hip/hip_runtime.h>
#include <math.h>

#define B_ 4
#define S_ 2048
#define D_ 1024
#define E_ 16
#define DH_ 64
#define TOPK_ 8
#define MAXLEN_ 1228
#define MPAD_ 1280
#define CAPF 4.0f
#define EPS_ 1e-6f

typedef __attribute__((ext_vector_type(8))) short bf16x8;
typedef __attribute__((ext_vector_type(4))) float f32x4;

__device__ inline f32x4 mfma16(bf16x8 a, bf16x8 b, f32x4 c) {
  return __builtin_amdgcn_mfma_f32_16x16x32_bf16(a, b, c, 0, 0, 0);
}
__device__ inline float bf2f(unsigned short u) {
  return __uint_as_float(((unsigned)u) << 16);
}
__device__ inline unsigned short f2bf(float f) {
  unsigned u = __float_as_uint(f);
  unsigned r = (u + 0x7FFFu + ((u >> 16) & 1u)) >> 16;
  return (unsigned short)r;
}
__device__ inline ushort4 pk4(float4 v) {
  ushort4 r;
  r.x = f2bf(v.x); r.y = f2bf(v.y); r.z = f2bf(v.z); r.w = f2bf(v.w);
  return r;
}
// XOR-swizzled LDS addressing (byte offsets), 128B rows.
__device__ inline int swz128(int row, int off) { return row * 128 + (off ^ ((row & 7) << 4)); }

// ---------------- one-time converts ----------------
// W_qkv[e][1024 k][192 n] f32 -> Wt[e][192 n][1024 k] bf16
__global__ __launch_bounds__(256) void cvt_wqkv_kernel(
    const float* __restrict__ W, unsigned short* __restrict__ Wt) {
  __shared__ short T[192][40];
  int e = blockIdx.y, k0 = blockIdx.x * 32;
  const float* Wp = W + (size_t)e * D_ * 192 + (size_t)k0 * 192;
  int tid = threadIdx.x;
#pragma unroll
  for (int it = 0; it < 24; it++) {
    int idx = tid + it * 256;  // 0..6143
    int kr = idx / 192, n = idx % 192;
    T[n][kr] = (short)f2bf(Wp[(size_t)kr * 192 + n]);
  }
  __syncthreads();
  unsigned short* Wo = Wt + (size_t)e * 192 * 1024 + k0;
#pragma unroll
  for (int it = 0; it < 3; it++) {
    int idx = tid + it * 256;  // 0..767
    int n = idx >> 2, c = idx & 3;
    bf16x8 v = *reinterpret_cast<bf16x8*>(&T[n][c * 8]);
    *reinterpret_cast<bf16x8*>(Wo + (size_t)n * 1024 + c * 8) = v;
  }
}

// W_ff[e][64 k][1024 n] f32 -> fragment-packed Wpk[e][64 nb][2 ks][64 l][8]
// lane l of frag (nb,ks) holds W[k=ks*32+(l>>4)*8 + j][n=nb*16+(l&15)]
__global__ __launch_bounds__(256) void cvt_wffpk_kernel(
    const float* __restrict__ W, unsigned short* __restrict__ Wpk) {
  int e = blockIdx.y;
  int nb = blockIdx.x * 4 + (threadIdx.x >> 6);
  int l = threadIdx.x & 63;
  int lr = l & 15, lg = l >> 4;
  const float* Wp = W + (size_t)e * DH_ * D_;
#pragma unroll
  for (int ks = 0; ks < 2; ks++) {
    bf16x8 v;
#pragma unroll
    for (int j = 0; j < 8; j++) {
      int k = ks * 32 + lg * 8 + j;
      int n = nb * 16 + lr;
      v[j] = (short)f2bf(Wp[(size_t)k * D_ + n]);
    }
    *reinterpret_cast<bf16x8*>(Wpk + ((((size_t)e * 64 + nb) * 2 + ks) * 64 + l) * 8) = v;
  }
}

// wg[1024 d][16 e] f32 -> wgT[16 e][1024 d] f32 (64 KB, one-time)
__global__ __launch_bounds__(256) void cvt_wgt_kernel(
    const float* __restrict__ wg, float* __restrict__ wgT) {
  int idx = blockIdx.x * 256 + threadIdx.x;  // 0..16383
  int e = idx >> 10, d = idx & 1023;
  wgT[idx] = wg[(size_t)d * E_ + e];
}

// bff[16 e][1024 n] f32 -> bffT[1024 n][32 k] bf16 (k=e for e<16, else 0)
__global__ __launch_bounds__(256) void cvt_bff_kernel(
    const float* __restrict__ bff, unsigned short* __restrict__ bffT) {
  int n = blockIdx.x * 256 + threadIdx.x;  // 0..1023
  unsigned short* o = bffT + (size_t)n * 32;
#pragma unroll
  for (int e = 0; e < E_; e++) o[e] = f2bf(bff[(size_t)e * D_ + n]);
#pragma unroll
  for (int e = E_; e < 32; e++) o[e] = 0;
}

// --------- Kernel 1: gating -> masked_t[e][b][s]; also emits Xb16 ---------
__global__ __launch_bounds__(256) void gate_kernel(
    const float* __restrict__ X, const float* __restrict__ wgT,
    const float* __restrict__ bg, float* __restrict__ masked_t,
    unsigned short* __restrict__ Xb) {
  int token = blockIdx.x * 4 + (threadIdx.x >> 6);  // b*S + s
  int lane = threadIdx.x & 63;
  int b = token / S_, s = token % S_;
  const float* xrow = X + (size_t)token * D_;
  unsigned short* xbrow = Xb + (size_t)token * D_;
  float acc[E_];
#pragma unroll
  for (int e = 0; e < E_; e++) acc[e] = 0.f;
#pragma unroll
  for (int d0 = 0; d0 < D_; d0 += 256) {
    int d = d0 + lane * 4;
    float4 xv = *reinterpret_cast<const float4*>(xrow + d);
    *reinterpret_cast<ushort4*>(xbrow + d) = pk4(xv);  // fused bf16 convert
#pragma unroll
    for (int e = 0; e < E_; e++) {
      float4 wv = *reinterpret_cast<const float4*>(wgT + (size_t)e * D_ + d);
      acc[e] += xv.x * wv.x + xv.y * wv.y + xv.z * wv.z + xv.w * wv.w;
    }
  }
#pragma unroll
  for (int e = 0; e < E_; e++) {
    float v = acc[e];
    for (int off = 32; off; off >>= 1) v += __shfl_xor(v, off);
    acc[e] = v;
  }
  if (lane == 0) {
    float lg[E_], sc[E_], mx = -1e30f;
#pragma unroll
    for (int e = 0; e < E_; e++) {
      lg[e] = acc[e] + bg[e];
      mx = fmaxf(mx, lg[e]);
    }
    float den = 0.f;
#pragma unroll
    for (int e = 0; e < E_; e++) {
      sc[e] = expf(lg[e] - mx);
      den += sc[e];
    }
#pragma unroll
    for (int e = 0; e < E_; e++) sc[e] /= den;
#pragma unroll
    for (int e = 0; e < E_; e++) {
      int rank = 0;
      for (int j = 0; j < E_; j++)
        if (lg[j] > lg[e] || (lg[j] == lg[e] && j < e)) rank++;
      float m = (rank < TOPK_) ? sc[e] : 0.f;
      masked_t[((size_t)e * B_ + b) * S_ + s] = m;
    }
  }
}

// ------- Kernel 3: radix-select top-MAXLEN per (e,b), route fused --------
__global__ __launch_bounds__(256) void select_kernel(
    const float* __restrict__ masked_t, int* __restrict__ seq_ids) {
  __shared__ unsigned vals[S_];
  __shared__ int hist[256];
  __shared__ int wsum[4];
  __shared__ int tsum[4];
  __shared__ unsigned sh_prefix;
  __shared__ int sh_rank;
  int eb = blockIdx.x;
  int e = eb >> 2, b = eb & 3;
  int tid = threadIdx.x;
  int lane = tid & 63, wv = tid >> 6;
  const float* mb0 = masked_t + (size_t)e * B_ * S_;
  for (int i = tid; i < S_; i += 256) {
    float v0 = mb0[i];
    float v1 = mb0[S_ + i];
    float v2 = mb0[2 * S_ + i];
    float v3 = mb0[3 * S_ + i];
    float d = EPS_;
    d += v0; d += v1; d += v2; d += v3;  // same order as route_kernel
    float mv = mb0[(size_t)b * S_ + i];
    vals[i] = __float_as_uint(mv / d * CAPF);
  }
  if (tid == 0) { sh_prefix = 0u; sh_rank = MAXLEN_; }
  __syncthreads();
  for (int shift = 24; shift >= 0; shift -= 8) {
    hist[tid] = 0;
    __syncthreads();
    unsigned pfx = sh_prefix;
    unsigned maskhi = (shift == 24) ? 0u : (0xFFFFFFFFu << (shift + 8));
    for (int i = tid; i < S_; i += 256) {
      unsigned v = vals[i];
      if ((v & maskhi) == pfx) atomicAdd(&hist[(v >> shift) & 255], 1);
    }
    __syncthreads();
    int bin = 255 - tid;
    int h = hist[bin];
    int sc = h;
    for (int off = 1; off < 64; off <<= 1) {
      int n = __shfl_up(sc, off);
      if (lane >= off) sc += n;
    }
    if (lane == 63) wsum[wv] = sc;
    __syncthreads();
    int add = 0;
#pragma unroll
    for (int k = 0; k < 4; k++)
      if (k < wv) add += wsum[k];
    sc += add;
    int rank = sh_rank;
    __syncthreads();
    if (sc - h < rank && rank <= sc) {
      sh_prefix = pfx | ((unsigned)bin << shift);
      sh_rank = rank - (sc - h);
    }
    __syncthreads();
  }
  unsigned T = sh_prefix;
  int r = sh_rank;
  int i0 = tid * 8;
  int eqf[8], gtf[8];
  int eqtot = 0;
#pragma unroll
  for (int k = 0; k < 8; k++) {
    unsigned v = vals[i0 + k];
    eqf[k] = (v == T) ? 1 : 0;
    gtf[k] = (v > T) ? 1 : 0;
    eqtot += eqf[k];
  }
  int esc = eqtot;
  for (int off = 1; off < 64; off <<= 1) {
    int n = __shfl_up(esc, off);
    if (lane >= off) esc += n;
  }
  if (lane == 63) tsum[wv] = esc;
  __syncthreads();
  int eadd = 0;
#pragma unroll
  for (int k = 0; k < 4; k++)
    if (k < wv) eadd += tsum[k];
  int erun = esc - eqtot + eadd;
  int self_[8];
  int stot = 0;
#pragma unroll
  for (int k = 0; k < 8; k++) {
    int s = gtf[k] | (eqf[k] & (erun < r ? 1 : 0));
    erun += eqf[k];
    self_[k] = s;
    stot += s;
  }
  __syncthreads();
  int ssc = stot;
  for (int off = 1; off < 64; off <<= 1) {
    int n = __shfl_up(ssc, off);
    if (lane >= off) ssc += n;
  }
  if (lane == 63) tsum[wv] = ssc;
  __syncthreads();
  int sadd = 0;
#pragma unroll
  for (int k = 0; k < 4; k++)
    if (k < wv) sadd += tsum[k];
  int pos = ssc - stot + sadd;
  int* outp = seq_ids + (size_t)eb * MAXLEN_;
#pragma unroll
  for (int k = 0; k < 8; k++) {
    if (self_[k]) outp[pos++] = i0 + k;
  }
}

// --------- Kernel 3b: inverse map inv[eb][s] = m (or -1) ---------
__global__ __launch_bounds__(256) void inv_kernel(
    const int* __restrict__ seq_ids, int* __restrict__ inv) {
  int eb = blockIdx.x;
  int tid = threadIdx.x;
  int* ip = inv + (size_t)eb * S_;
  for (int i = tid; i < S_; i += 256) ip[i] = -1;
  __syncthreads();
  const int* sid = seq_ids + (size_t)eb * MAXLEN_;
  for (int m = tid; m < MAXLEN_; m += 256) ip[sid[m]] = m;
}

// ---------------- Kernel 4: gathered QKV GEMM (bf16 MFMA) ----------------
__global__ __launch_bounds__(512) void qkv_kernel(
    const unsigned short* __restrict__ Xb, const unsigned short* __restrict__ Wt,
    const int* __restrict__ seq_ids, unsigned short* __restrict__ Qr,
    unsigned short* __restrict__ Kr, unsigned short* __restrict__ VT) {
  __shared__ __align__(16) char Bt_[2][192 * 128];  // [192 n][64 k] bf16 swz128
  __shared__ int rows[128];
  int eb = blockIdx.y;
  int e = eb >> 2, b = eb & 3;
  int m0 = blockIdx.x * 128;
  int tid = threadIdx.x;
  int w = tid >> 6, l = tid & 63, lr = l & 15, lg = l >> 4;
  int wm = w & 3, wn = w >> 2;
  const int* sid = seq_ids + (size_t)eb * MAXLEN_;
  if (tid < 128) {
    int m = m0 + tid;
    rows[tid] = (m < MAXLEN_) ? sid[m] : 0;
  }
  __syncthreads();
  const unsigned short* Wm = Wt + (size_t)e * 192 * 1024;
  const unsigned short* Xbb = Xb + (size_t)b * S_ * D_;
  const unsigned short* ap0 = Xbb + (size_t)rows[wm * 32 + lr] * D_;
  const unsigned short* ap1 = Xbb + (size_t)rows[wm * 32 + 16 + lr] * D_;
  int s0 = tid, s1 = tid + 512, s2 = tid + 1024;
  f32x4 acc[2][6];
#pragma unroll
  for (int a = 0; a < 2; a++)
#pragma unroll
    for (int j = 0; j < 6; j++) acc[a][j] = (f32x4){0.f, 0.f, 0.f, 0.f};
  bf16x8 stg0 = *reinterpret_cast<const bf16x8*>(Wm + (size_t)(s0 >> 3) * 1024 + (s0 & 7) * 8);
  bf16x8 stg1 = *reinterpret_cast<const bf16x8*>(Wm + (size_t)(s1 >> 3) * 1024 + (s1 & 7) * 8);
  bf16x8 stg2 = *reinterpret_cast<const bf16x8*>(Wm + (size_t)(s2 >> 3) * 1024 + (s2 & 7) * 8);
  bf16x8 a00 = *reinterpret_cast<const bf16x8*>(ap0 + lg * 8);
  bf16x8 a01 = *reinterpret_cast<const bf16x8*>(ap0 + 32 + lg * 8);
  bf16x8 a10 = *reinterpret_cast<const bf16x8*>(ap1 + lg * 8);
  bf16x8 a11 = *reinterpret_cast<const bf16x8*>(ap1 + 32 + lg * 8);
  for (int t = 0; t < 16; t++) {
    char* buf = Bt_[t & 1];
    *reinterpret_cast<bf16x8*>(buf + swz128(s0 >> 3, (s0 & 7) * 16)) = stg0;
    *reinterpret_cast<bf16x8*>(buf + swz128(s1 >> 3, (s1 & 7) * 16)) = stg1;
    *reinterpret_cast<bf16x8*>(buf + swz128(s2 >> 3, (s2 & 7) * 16)) = stg2;
    bf16x8 n0, n1, n2, b00, b01, b10, b11;
    if (t < 15) {
      int kn = (t + 1) * 64;
      n0 = *reinterpret_cast<const bf16x8*>(Wm + (size_t)(s0 >> 3) * 1024 + kn + (s0 & 7) * 8);
      n1 = *reinterpret_cast<const bf16x8*>(Wm + (size_t)(s1 >> 3) * 1024 + kn + (s1 & 7) * 8);
      n2 = *reinterpret_cast<const bf16x8*>(Wm + (size_t)(s2 >> 3) * 1024 + kn + (s2 & 7) * 8);
      b00 = *reinterpret_cast<const bf16x8*>(ap0 + kn + lg * 8);
      b01 = *reinterpret_cast<const bf16x8*>(ap0 + kn + 32 + lg * 8);
      b10 = *reinterpret_cast<const bf16x8*>(ap1 + kn + lg * 8);
      b11 = *reinterpret_cast<const bf16x8*>(ap1 + kn + 32 + lg * 8);
    }
    __syncthreads();
#pragma unroll
    for (int j = 0; j < 6; j++) {
      int nr = (wn * 6 + j) * 16 + lr;
      bf16x8 bf0 = *reinterpret_cast<bf16x8*>(buf + swz128(nr, lg * 16));
      bf16x8 bf1 = *reinterpret_cast<bf16x8*>(buf + swz128(nr, 64 + lg * 16));
      acc[0][j] = mfma16(a00, bf0, acc[0][j]);
      acc[1][j] = mfma16(a10, bf0, acc[1][j]);
      acc[0][j] = mfma16(a01, bf1, acc[0][j]);
      acc[1][j] = mfma16(a11, bf1, acc[1][j]);
    }
    if (t < 15) {
      stg0 = n0; stg1 = n1; stg2 = n2;
      a00 = b00; a01 = b01; a10 = b10; a11 = b11;
    }
  }
  unsigned short* Qe = Qr + (size_t)eb * MPAD_ * 64;
  unsigned short* Ke = Kr + (size_t)eb * MPAD_ * 64;
  unsigned short* Ve = VT + (size_t)eb * 64 * MPAD_;
#pragma unroll
  for (int a = 0; a < 2; a++) {
    int mb = m0 + wm * 32 + a * 16 + lg * 4;
#pragma unroll
    for (int j = 0; j < 6; j++) {
      int nbg = wn * 6 + j;
      if (nbg < 4) {
#pragma unroll
        for (int i = 0; i < 4; i++) {
          int m = mb + i;
          float v = (m < MAXLEN_) ? acc[a][j][i] * 0.125f : 0.f;
          Qe[(size_t)m * 64 + nbg * 16 + lr] = f2bf(v);
        }
      } else if (nbg < 8) {
#pragma unroll
        for (int i = 0; i < 4; i++) {
          int m = mb + i;
          float v = (m < MAXLEN_) ? acc[a][j][i] : 0.f;
          Ke[(size_t)m * 64 + (nbg - 4) * 16 + lr] = f2bf(v);
        }
      } else {
        ushort4 pv;
        pv.x = (mb + 0 < MAXLEN_) ? f2bf(acc[a][j][0]) : (unsigned short)0;
        pv.y = (mb + 1 < MAXLEN_) ? f2bf(acc[a][j][1]) : (unsigned short)0;
        pv.z = (mb + 2 < MAXLEN_) ? f2bf(acc[a][j][2]) : (unsigned short)0;
        pv.w = (mb + 3 < MAXLEN_) ? f2bf(acc[a][j][3]) : (unsigned short)0;
        *reinterpret_cast<ushort4*>(Ve + (size_t)((nbg - 8) * 16 + lr) * MPAD_ + mb) = pv;
      }
    }
  }
}

// ------------- Kernel 5: flash attention, bf16 MFMA, per (e,b) -------------
__global__ __launch_bounds__(512) void attn_kernel(
    const unsigned short* __restrict__ Qr, const unsigned short* __restrict__ Kr,
    const unsigned short* __restrict__ VT, unsigned short* __restrict__ ctx) {
  __shared__ __align__(16) char Ks_[64 * 128];      // [64 k][64 d] swz128
  __shared__ __align__(16) char Vt_[64 * 128];      // [64 dv][64 k] swz128
  __shared__ __align__(16) char Pl_[8 * 16 * 128];  // per-wave [16 q][64 k]
  int qb = 9 - blockIdx.x;  // longest first
  int eb = blockIdx.y;
  const unsigned short* Qe = Qr + (size_t)eb * MPAD_ * 64;
  const unsigned short* Ke = Kr + (size_t)eb * MPAD_ * 64;
  const unsigned short* Ve = VT + (size_t)eb * 64 * MPAD_;
  int tid = threadIdx.x;
  int w = tid >> 6, l = tid & 63, lr = l & 15, lg = l >> 4;
  int gq = qb * 128 + w * 16 + lr;
  bf16x8 qf[2];
  qf[0] = *reinterpret_cast<const bf16x8*>(Qe + (size_t)gq * 64 + lg * 8);
  qf[1] = *reinterpret_cast<const bf16x8*>(Qe + (size_t)gq * 64 + 32 + lg * 8);
  f32x4 acc[4];
#pragma unroll
  for (int db = 0; db < 4; db++) acc[db] = (f32x4){0.f, 0.f, 0.f, 0.f};
  float mrow = -1e30f, lsum = 0.f;
  char* Pw = Pl_ + w * 2048;
  int srow = tid >> 3, sc = (tid & 7) * 8;
  int ndiag = 2 * qb, ktmax = 2 * qb + 1;
  for (int kt = 0; kt <= ktmax; kt++) {
    int k0 = kt * 64;
    {
      bf16x8 kv = *reinterpret_cast<const bf16x8*>(Ke + (size_t)(k0 + srow) * 64 + sc);
      *reinterpret_cast<bf16x8*>(Ks_ + swz128(srow, sc * 2)) = kv;
      bf16x8 vv = *reinterpret_cast<const bf16x8*>(Ve + (size_t)srow * MPAD_ + k0 + sc);
      *reinterpret_cast<bf16x8*>(Vt_ + swz128(srow, sc * 2)) = vv;
    }
    __syncthreads();
    f32x4 sac[4];
#pragma unroll
    for (int kb = 0; kb < 4; kb++) {
      sac[kb] = (f32x4){0.f, 0.f, 0.f, 0.f};
#pragma unroll
      for (int ds = 0; ds < 2; ds++) {
        bf16x8 kf = *reinterpret_cast<bf16x8*>(Ks_ + swz128(kb * 16 + lr, ds * 64 + lg * 16));
        sac[kb] = mfma16(kf, qf[ds], sac[kb]);
      }
    }
    float p[16];
    float tmax = -1e30f;
    if (kt >= ndiag) {
#pragma unroll
      for (int kb = 0; kb < 4; kb++) {
#pragma unroll
        for (int i = 0; i < 4; i++) {
          int k = k0 + kb * 16 + lg * 4 + i;
          float s = sac[kb][i];
          if (k > gq || k >= MAXLEN_) s = -1e9f;
          p[kb * 4 + i] = s;
          tmax = fmaxf(tmax, s);
        }
      }
    } else {
#pragma unroll
      for (int kb = 0; kb < 4; kb++) {
#pragma unroll
        for (int i = 0; i < 4; i++) {
          float s = sac[kb][i];
          p[kb * 4 + i] = s;
          tmax = fmaxf(tmax, s);
        }
      }
    }
    tmax = fmaxf(tmax, __shfl_xor(tmax, 16));
    tmax = fmaxf(tmax, __shfl_xor(tmax, 32));
    if (!__all(tmax <= mrow + 8.f)) {
      float mnew = fmaxf(mrow, tmax);
      float corr = __expf(mrow - mnew);
      lsum *= corr;
#pragma unroll
      for (int db = 0; db < 4; db++) acc[db] = acc[db] * corr;
      mrow = mnew;
    }
    float psum = 0.f;
#pragma unroll
    for (int j = 0; j < 16; j++) {
      p[j] = __expf(p[j] - mrow);
      psum += p[j];
    }
    psum += __shfl_xor(psum, 16);
    psum += __shfl_xor(psum, 32);
    lsum += psum;
#pragma unroll
    for (int kb = 0; kb < 4; kb++) {
#pragma unroll
      for (int ip = 0; ip < 2; ip++) {
        unsigned u = (unsigned)f2bf(p[kb * 4 + ip * 2]) |
                     ((unsigned)f2bf(p[kb * 4 + ip * 2 + 1]) << 16);
        int k = kb * 16 + lg * 4 + ip * 2;
        *reinterpret_cast<unsigned*>(Pw + swz128(lr, k * 2)) = u;
      }
    }
    bf16x8 pf[2];
#pragma unroll
    for (int ks = 0; ks < 2; ks++)
      pf[ks] = *reinterpret_cast<bf16x8*>(Pw + swz128(lr, ks * 64 + lg * 16));
#pragma unroll
    for (int db = 0; db < 4; db++) {
#pragma unroll
      for (int ks = 0; ks < 2; ks++) {
        bf16x8 vf = *reinterpret_cast<bf16x8*>(Vt_ + swz128(db * 16 + lr, ks * 64 + lg * 16));
        acc[db] = mfma16(vf, pf[ks], acc[db]);
      }
    }
    __syncthreads();
  }
  if (gq < MAXLEN_) {
    float inv = 1.f / lsum;
    unsigned short* op = ctx + ((size_t)eb * MAXLEN_ + gq) * DH_;
#pragma unroll
    for (int db = 0; db < 4; db++) {
      ushort4 pv;
      pv.x = f2bf(acc[db][0] * inv);
      pv.y = f2bf(acc[db][1] * inv);
      pv.z = f2bf(acc[db][2] * inv);
      pv.w = f2bf(acc[db][3] * inv);
      *reinterpret_cast<ushort4*>(op + db * 16 + lg * 4) = pv;
    }
  }
}

// --- Kernel 6: fused FF + expert-sum + residual + LayerNorm ---
// 1024 threads / 16 waves; wave w owns cols [w*64, w*64+64).
// B loads from fragment-packed Wpk: one contiguous 1KB access per frag.
__global__ __launch_bounds__(1024) void ffgl_kernel(
    const float* __restrict__ X, const unsigned short* __restrict__ ctx,
    const unsigned short* __restrict__ Wpk, const unsigned short* __restrict__ bffT,
    const int* __restrict__ inv, const float* __restrict__ gamma,
    const float* __restrict__ beta, float* __restrict__ out) {
  __shared__ int invs[E_][32];
  __shared__ __align__(16) char As_[2][32 * 128];  // [32 m][64 k] bf16 swz128
  __shared__ float red1[16][32], red2[16][32];
  __shared__ float mu_s[32], ri_s[32];
  int st = blockIdx.x, b = blockIdx.y;
  int s0 = st * 32;
  int tid = threadIdx.x;
  int w = tid >> 6, l = tid & 63, lr = l & 15, lg = l >> 4;
  // early: X residual into registers (in flight under the expert loop)
  float xreg[2][4][4];
#pragma unroll
  for (int a = 0; a < 2; a++)
#pragma unroll
    for (int j = 0; j < 4; j++) {
      int col = w * 64 + j * 16 + lr;
#pragma unroll
      for (int i = 0; i < 4; i++) {
        int row = a * 16 + lg * 4 + i;
        xreg[a][j][i] = X[((size_t)b * S_ + s0 + row) * D_ + col];
      }
    }
  if (tid < 512) {
    int e = tid >> 5, i = tid & 31;
    invs[e][i] = inv[((size_t)(e * B_ + b)) * S_ + s0 + i];
  }
  __syncthreads();
  int si = tid >> 5, sq = tid & 31;  // staging: row si, 4-byte chunk sq
  {
    int m = invs[0][si];
    ushort2 v = {0, 0};
    if (m >= 0)
      v = *reinterpret_cast<const ushort2*>(ctx + ((size_t)(0 * B_ + b) * MAXLEN_ + m) * DH_ + sq * 2);
    *reinterpret_cast<ushort2*>(As_[0] + swz128(si, sq * 4)) = v;
  }
  f32x4 acc[2][4];
#pragma unroll
  for (int a = 0; a < 2; a++)
#pragma unroll
    for (int j = 0; j < 4; j++) acc[a][j] = (f32x4){0.f, 0.f, 0.f, 0.f};
#pragma unroll 1
  for (int e = 0; e < E_; e++) {
    __syncthreads();
    if (e < E_ - 1) {  // prefetch-stage next expert's A tile into other buffer
      int m = invs[e + 1][si];
      ushort2 v = {0, 0};
      if (m >= 0)
        v = *reinterpret_cast<const ushort2*>(ctx + ((size_t)((e + 1) * B_ + b) * MAXLEN_ + m) * DH_ + sq * 2);
      *reinterpret_cast<ushort2*>(As_[(e + 1) & 1] + swz128(si, sq * 4)) = v;
    }
    const char* Ab = As_[e & 1];
    bf16x8 af[2][2];
#pragma unroll
    for (int a = 0; a < 2; a++)
#pragma unroll
      for (int ks = 0; ks < 2; ks++)
        af[a][ks] = *reinterpret_cast<const bf16x8*>(Ab + swz128(a * 16 + lr, ks * 64 + lg * 16));
    const unsigned short* We = Wpk + (size_t)e * 65536;  // 64 nb * 2 ks * 64 l * 8
#pragma unroll
    for (int j = 0; j < 4; j++) {
      int nbi = w * 4 + j;
      bf16x8 b0 = *reinterpret_cast<const bf16x8*>(We + (((size_t)nbi * 2 + 0) * 64 + l) * 8);
      bf16x8 b1 = *reinterpret_cast<const bf16x8*>(We + (((size_t)nbi * 2 + 1) * 64 + l) * 8);
      acc[0][j] = mfma16(af[0][0], b0, acc[0][j]);
      acc[1][j] = mfma16(af[1][0], b0, acc[1][j]);
      acc[0][j] = mfma16(af[0][1], b1, acc[0][j]);
      acc[1][j] = mfma16(af[1][1], b1, acc[1][j]);
    }
  }
  // bias pass: A = selection matrix S[32 rows][32 k] (k=e<16), B = bffT
  {
    bf16x8 afb[2];
#pragma unroll
    for (int a = 0; a < 2; a++) {
#pragma unroll
      for (int t = 0; t < 8; t++) {
        int k = lg * 8 + t;
        unsigned short u = 0;
        if (k < E_ && invs[k][a * 16 + lr] >= 0) u = 0x3F80;  // 1.0bf16
        afb[a][t] = (short)u;
      }
    }
#pragma unroll
    for (int j = 0; j < 4; j++) {
      int n = w * 64 + j * 16 + lr;
      bf16x8 bb = *reinterpret_cast<const bf16x8*>(bffT + (size_t)n * 32 + lg * 8);
      acc[0][j] = mfma16(afb[0], bb, acc[0][j]);
      acc[1][j] = mfma16(afb[1], bb, acc[1][j]);
    }
  }
  // epilogue: + X residual (prefetched), row stats, LayerNorm, store f32
  float p1[2][4], p2[2][4];
#pragma unroll
  for (int a = 0; a < 2; a++)
#pragma unroll
    for (int i = 0; i < 4; i++) { p1[a][i] = 0.f; p2[a][i] = 0.f; }
#pragma unroll
  for (int a = 0; a < 2; a++) {
#pragma unroll
    for (int j = 0; j < 4; j++) {
#pragma unroll
      for (int i = 0; i < 4; i++) {
        float v = acc[a][j][i] + xreg[a][j][i];
        acc[a][j][i] = v;
        p1[a][i] += v;
        p2[a][i] += v * v;
      }
    }
  }
#pragma unroll
  for (int a = 0; a < 2; a++)
#pragma unroll
    for (int i = 0; i < 4; i++) {
#pragma unroll
      for (int off = 1; off < 16; off <<= 1) {
        p1[a][i] += __shfl_xor(p1[a][i], off);
        p2[a][i] += __shfl_xor(p2[a][i], off);
      }
    }
  if (lr == 0) {
#pragma unroll
    for (int a = 0; a < 2; a++)
#pragma unroll
      for (int i = 0; i < 4; i++) {
        int row = a * 16 + lg * 4 + i;
        red1[w][row] = p1[a][i];
        red2[w][row] = p2[a][i];
      }
  }
  __syncthreads();
  if (tid < 32) {
    float s1 = 0.f, s2 = 0.f;
#pragma unroll
    for (int w2 = 0; w2 < 16; w2++) { s1 += red1[w2][tid]; s2 += red2[w2][tid]; }
    float mu = s1 * (1.f / D_);
    float var = s2 * (1.f / D_) - mu * mu;
    mu_s[tid] = mu;
    ri_s[tid] = rsqrtf(var + 1e-5f);
  }
  __syncthreads();
#pragma unroll
  for (int a = 0; a < 2; a++) {
#pragma unroll
    for (int j = 0; j < 4; j++) {
      int col = w * 64 + j * 16 + lr;
      float g = gamma[col];
      float be = beta[col];
#pragma unroll
      for (int i = 0; i < 4; i++) {
        int row = a * 16 + lg * 4 + i;
        out[((size_t)b * S_ + s0 + row) * D_ + col] =
            (acc[a][j][i] - mu_s[row]) * ri_s[row] * g + be;
      }
    }
  }
}

extern "C" void kernel_launch(void* const* d_in, const int* in_sizes, int n_in,
                              void* d_out, int out_size, void* d_ws, size_t ws_size,
                              hipStream_t stream) {
  const float* X = (const float*)d_in[0];
  // d_in[1] = attn_mask (causal, hardcoded)
  const float* w_gate = (const float*)d_in[2];
  const float* b_gate = (const float*)d_in[3];
  const float* W_qkv = (const float*)d_in[4];
  const float* W_ff = (const float*)d_in[5];
  const float* b_ff = (const float*)d_in[6];
  const float* ln_g = (const float*)d_in[7];
  const float* ln_b = (const float*)d_in[8];
  float* out = (float*)d_out;

  char* ws = (char*)d_ws;
  float* masked_t = (float*)(ws);                           //   524288 B
  int* seq_ids = (int*)(ws + 1048576);                      //   314368 B
  unsigned short* Qr = (unsigned short*)(ws + 1362944);     // 10485760 B
  unsigned short* Kr = (unsigned short*)(ws + 11848704);    // 10485760 B
  unsigned short* VT = (unsigned short*)(ws + 22334464);    // 10485760 B
  unsigned short* ctx = (unsigned short*)(ws + 32820224);   // 10059776 B
  unsigned short* Xb16 = (unsigned short*)(ws + 42880000);  // 16777216 B
  unsigned short* Wtq = (unsigned short*)(ws + 59657216);   //  6291456 B
  unsigned short* Wpk = (unsigned short*)(ws + 65948672);   //  2097152 B
  float* wgT = (float*)(ws + 68045824);                     //    65536 B
  unsigned short* bffT = (unsigned short*)(ws + 68111360);  //    65536 B
  int* inv = (int*)(ws + 68176896);                         //   524288 B
  // total 68701184 B

  cvt_wqkv_kernel<<<dim3(32, 16), 256, 0, stream>>>(W_qkv, Wtq);
  cvt_wffpk_kernel<<<dim3(16, 16), 256, 0, stream>>>(W_ff, Wpk);
  cvt_wgt_kernel<<<64, 256, 0, stream>>>(w_gate, wgT);
  cvt_bff_kernel<<<4, 256, 0, stream>>>(b_ff, bffT);
  gate_kernel<<<2048, 256, 0, stream>>>(X, wgT, b_gate, masked_t, Xb16);
  select_kernel<<<E_ * B_, 256, 0, stream>>>(masked_t, seq_ids);
  inv_kernel<<<E_ * B_, 256, 0, stream>>>(seq_ids, inv);
  qkv_kernel<<<dim3(10, 64), 512, 0, stream>>>(Xb16, Wtq, seq_ids, Qr, Kr, VT);
  attn_kernel<<<dim3(10, 64), 512, 0, stream>>>(Qr, Kr, VT, ctx);
  ffgl_kernel<<<dim3(S_ / 32, B_), 1024, 0, stream>>>(X, ctx, Wpk, bffT, inv,
                                                      ln_g, ln_b, out);
}